// Round 8
// baseline (897.559 us; speedup 1.0000x reference)
//
#include <hip/hip_runtime.h>

// ---------------------------------------------------------------------------
// GAE_IR_79499844649397. Atomic-free pipeline.
// Big GEMMs: 256x256 tile, BK=32, LDS 64KB dbuf, 2 blocks/CU. Minimal-sync
// K-loop: ONE s_barrier + ONE counted vmcnt(4) per K-tile, no lgkm asm, no
// phases (HW scheduler overlaps ds_read/MFMA/staging). Slot-XOR LDS swizzle,
// XCD chunked swizzle.
// ---------------------------------------------------------------------------

typedef unsigned short u16;
typedef __bf16 bf16x8 __attribute__((ext_vector_type(8)));
typedef float f32x4 __attribute__((ext_vector_type(4)));

__device__ inline u16 f2bf_u(float f) {
  union { float f; unsigned u; } a; a.f = f;
  unsigned u = a.u + 0x7fffu + ((a.u >> 16) & 1u);   // RNE
  return (u16)(u >> 16);
}
__device__ inline float bf2f_u(u16 h) {
  union { unsigned u; float f; } a; a.u = ((unsigned)h) << 16; return a.f;
}

#define GLOAD16(gptr, lptr)                                                   \
  __builtin_amdgcn_global_load_lds(                                           \
      (__attribute__((address_space(1))) void*)(gptr),                        \
      (__attribute__((address_space(3))) void*)(lptr), 16, 0, 0)

#define BAR  __builtin_amdgcn_s_barrier()
#define VMC4 asm volatile("s_waitcnt vmcnt(4)" ::: "memory")
#define VMC0 asm volatile("s_waitcnt vmcnt(0)" ::: "memory")

struct Panel {
  const u16* A; int lda;
  const u16* B; int ldb;
  const float* bias; int biasN;
  int N; int nK;               // nK in units of 32
  void* out; int ldc;
  const float* rsVec;          // optional per-row scale (pre-rsqrt'd)
  const float* addS;           // optional gathered row-add (f32, ld 4096)
};

// MODE 0: bf16 out, v = relu(acc*rs + bias + S[b])
// MODE 1: bf16 out + bias, + rowsq partials
// MODE 3: f32 out + bias, 3-range remap + rowsq partials
template <int MODE>
__global__ __launch_bounds__(512, 2) void gemm256(
    Panel p0, Panel p1, int yb,
    float* __restrict__ rsPart, int rsLd,
    float* __restrict__ cTheta, float* __restrict__ cNeg, float* __restrict__ cTgt) {
  __shared__ u16 As[2][8192];   // [256][32] x2
  __shared__ u16 Bs[2][8192];

  // chunked-bijective XCD swizzle
  const int nwg = gridDim.x * gridDim.y;
  const int orig = blockIdx.y * gridDim.x + blockIdx.x;
  const int q = nwg >> 3, r = nwg & 7, xcd = orig & 7;
  const int basewg = (xcd < r) ? xcd * (q + 1) : r * (q + 1) + (xcd - r) * q;
  const int wg = basewg + (orig >> 3);
  const int bx = wg % gridDim.x, by = wg / gridDim.x;

  const Panel P = (by < yb) ? p0 : p1;
  const int rowOff = (by < yb) ? 0 : (yb << 8);
  const int m0g = by << 8;
  const int m0 = m0g - rowOff;
  const int n0 = bx << 8;

  const int tid = threadIdx.x;
  const int wave = tid >> 6, lane = tid & 63;
  const int lr = lane & 15, lg = lane >> 4;   // lg in 0..3 (slot)
  const int wr = wave >> 2, wc = wave & 3;

  f32x4 acc[8][4] = {};

  // Staging: LDS[row][sc] = G[row][sc ^ ((row>>1)&3)], linear dest (rule 21).
  const int r7 = tid >> 2, sc0 = tid & 3;
  const int ra = (r7 & 63) | ((r7 & 64) << 1);
  const int swA = (ra >> 1) & 3;   // same for ra and ra+64
  const size_t aAL = (size_t)(m0 + ra) * P.lda + ((sc0 ^ swA) << 3);
  const size_t aAH = (size_t)(m0 + ra + 64) * P.lda + ((sc0 ^ swA) << 3);
  const int lAL = (ra * 4 + sc0) << 4;          // byte offsets
  const int lAH = ((ra + 64) * 4 + sc0) << 4;
  size_t bSrc[2]; int lB[2];
#pragma unroll
  for (int i = 0; i < 2; ++i) {
    const int c = tid + (i << 9);
    const int row = c >> 2, sc = c & 3;
    bSrc[i] = (size_t)(n0 + row) * P.ldb + ((sc ^ ((row >> 1) & 3)) << 3);
    lB[i] = c << 4;
  }

  auto stage = [&](int kt, int b) {
    const int k0 = kt << 5;
    GLOAD16(P.A + aAL + k0, (char*)As[b] + lAL);
    GLOAD16(P.A + aAH + k0, (char*)As[b] + lAH);
    GLOAD16(P.B + bSrc[0] + k0, (char*)Bs[b] + lB[0]);
    GLOAD16(P.B + bSrc[1] + k0, (char*)Bs[b] + lB[1]);
  };

  bf16x8 af[4], bv[4];
  auto rdA = [&](const u16* Ab, int qm) {
#pragma unroll
    for (int mf = 0; mf < 4; ++mf) {
      const int row = (wr << 7) + qm * 64 + mf * 16 + lr;
      af[mf] = *(const bf16x8*)(Ab + row * 32 + ((lg ^ ((row >> 1) & 3)) << 3));
    }
  };
  auto rdB = [&](const u16* Bb) {
#pragma unroll
    for (int nf = 0; nf < 4; ++nf) {
      const int row = (wc << 6) + nf * 16 + lr;
      bv[nf] = *(const bf16x8*)(Bb + row * 32 + ((lg ^ ((row >> 1) & 3)) << 3));
    }
  };
  auto mm = [&](int qm) {
#pragma unroll
    for (int mf = 0; mf < 4; ++mf)
#pragma unroll
      for (int nf = 0; nf < 4; ++nf)
        acc[qm * 4 + mf][nf] = __builtin_amdgcn_mfma_f32_16x16x32_bf16(
            af[mf], bv[nf], acc[qm * 4 + mf][nf], 0, 0, 0);
  };

  // Minimal-sync loop: per tile {BAR; stage(t+1); vmcnt(4); reads+MFMA}.
  // stage(t+1) overwrites buf of tile t-1, whose reads drained before BAR
  // (every ds_read feeds an MFMA issued pre-barrier -> compiler lgkmcnt).
  const int nK = P.nK;
  stage(0, 0);
  for (int t = 0; t < nK; ++t) {
    const int cur = t & 1;
    BAR;
    if (t + 1 < nK) { stage(t + 1, cur ^ 1); VMC4; }
    else { VMC0; }
    const u16* Ab = As[cur];
    const u16* Bb = Bs[cur];
    rdA(Ab, 0); rdB(Bb);
    mm(0);
    rdA(Ab, 1);
    mm(1);
  }

  const int gcb = n0 + (wc << 6);
  const int grb = m0 + (wr << 7) + (lg << 2);
  const int grbG = m0g + (wr << 7) + (lg << 2);
#pragma unroll
  for (int m = 0; m < 8; ++m) {
#pragma unroll
    for (int rr = 0; rr < 4; ++rr) {
      const int grow = grb + (m << 4) + rr;
      const int growG = grbG + (m << 4) + rr;
      float ss = 0.f;
      float rs = 1.f;
      const float* Sp = nullptr;
      if (MODE == 0) {
        if (P.rsVec) rs = P.rsVec[growG];
        if (P.addS) {
          int bv2 = (growG < 256) ? growG : (growG - 256) / 114;
          Sp = P.addS + (size_t)bv2 * 4096;
        }
      }
#pragma unroll
      for (int n = 0; n < 4; ++n) {
        const int gc = gcb + (n << 4) + lr;
        if (gc >= P.N) continue;
        float v = acc[m][n][rr];
        if (MODE == 0) {
          v *= rs;
          if (gc < P.biasN) v += P.bias[gc];
          if (Sp) v += Sp[gc];
          v = fmaxf(v, 0.f);
          ((u16*)P.out)[(size_t)grow * P.ldc + gc] = f2bf_u(v);
        } else if (MODE == 1) {
          if (gc < P.biasN) v += P.bias[gc];
          ((u16*)P.out)[(size_t)grow * P.ldc + gc] = f2bf_u(v);
          ss += v * v;
        } else {
          if (gc < P.biasN) v += P.bias[gc];
          float* op = (growG < 256) ? cTheta + (size_t)growG * 800
                    : (growG < 29440) ? cNeg + (size_t)(growG - 256) * 800
                                      : cTgt + (size_t)(growG - 29440) * 800;
          op[gc] = v;
          ss += v * v;
        }
      }
      if (MODE == 1 || MODE == 3) {
        ss += __shfl_xor(ss, 1); ss += __shfl_xor(ss, 2);
        ss += __shfl_xor(ss, 4); ss += __shfl_xor(ss, 8);
        if (lr == 0) rsPart[(size_t)((bx << 2) + wc) * rsLd + growG] = ss;
      }
    }
  }
}

// ---------------------------------------------------------------------------
// Small-M GEMM: 128x128, BK=32. STORE=1 plain store; else z-partial store.
// ---------------------------------------------------------------------------
template <int STORE>
__global__ __launch_bounds__(256) void gemm_atom(
    const u16* __restrict__ A, int lda, const u16* __restrict__ Bt, int ldb,
    int N, int nK, int ktChunk, float* __restrict__ Cf, int ldc, int zStride) {
  __shared__ u16 As[2][4096];
  __shared__ u16 Bs[2][4096];
  const int tid = threadIdx.x;
  const int wave = tid >> 6, lane = tid & 63;
  const int lr = lane & 15, lg = lane >> 4;
  const int wr = wave >> 1, wc = wave & 1;
  const int m0 = blockIdx.y << 7, n0 = blockIdx.x << 7;

  f32x4 acc[4][4] = {};

  const size_t aOff  = (size_t)(m0 + (tid >> 2)) * lda + ((tid & 3) << 3);
  const size_t aOff1 = aOff + (size_t)64 * lda;
  const size_t bOff  = (size_t)(n0 + (tid >> 2)) * ldb + ((tid & 3) << 3);
  const size_t bOff1 = bOff + (size_t)64 * ldb;

  const int kt0 = blockIdx.z * ktChunk;
  int ktEnd = kt0 + ktChunk; if (ktEnd > nK) ktEnd = nK;

  auto stage = [&](int kt, int b) {
    const int k0 = kt << 5;
    u16* Ad = &As[b][wave << 9];
    u16* Bd = &Bs[b][wave << 9];
    GLOAD16(A + aOff + k0, Ad);
    GLOAD16(A + aOff1 + k0, Ad + 2048);
    GLOAD16(Bt + bOff + k0, Bd);
    GLOAD16(Bt + bOff1 + k0, Bd + 2048);
  };

  if (kt0 < ktEnd) stage(kt0, 0);
  for (int kt = kt0; kt < ktEnd; ++kt) {
    const int cb = (kt - kt0) & 1;
    if (kt + 1 < ktEnd) {
      stage(kt + 1, cb ^ 1);
      VMC4;
    } else {
      VMC0;
    }
    BAR;
    asm volatile("" ::: "memory");

    bf16x8 af[4], bvv[4];
#pragma unroll
    for (int m = 0; m < 4; ++m)
      af[m] = *(const bf16x8*)(&As[cb][(((wr << 6) + (m << 4) + lr) << 5) + (lg << 3)]);
#pragma unroll
    for (int n = 0; n < 4; ++n)
      bvv[n] = *(const bf16x8*)(&Bs[cb][(((wc << 6) + (n << 4) + lr) << 5) + (lg << 3)]);
#pragma unroll
    for (int m = 0; m < 4; ++m)
#pragma unroll
      for (int n = 0; n < 4; ++n)
        acc[m][n] = __builtin_amdgcn_mfma_f32_16x16x32_bf16(af[m], bvv[n], acc[m][n], 0, 0, 0);

    asm volatile("s_waitcnt lgkmcnt(0)" ::: "memory");
    BAR;
    asm volatile("" ::: "memory");
  }

  float* out = STORE ? Cf : (Cf + (size_t)blockIdx.z * zStride);
  const int gcb = n0 + (wc << 6);
  const int grb = m0 + (wr << 6) + (lg << 2);
#pragma unroll
  for (int m = 0; m < 4; ++m)
#pragma unroll
    for (int rr = 0; rr < 4; ++rr) {
      const int grow = grb + (m << 4) + rr;
#pragma unroll
      for (int n = 0; n < 4; ++n) {
        const int gc = gcb + (n << 4) + lr;
        if (gc < N) out[(size_t)grow * ldc + gc] = acc[m][n][rr];
      }
    }
}

// --------------------------- weight packing --------------------------------
struct PJob { const float* src; u16* dst; int Ksrc, Nsrc, Kpad, Npad, ld; };
struct PJobs { PJob j[10]; };

__global__ void k_pack10(PJobs J) {
  PJob job = J.j[blockIdx.z];
  const int k0 = blockIdx.x * 16, n0 = blockIdx.y * 16;
  if (k0 >= job.Kpad || n0 >= job.Npad) return;
  __shared__ float t[16][17];
  const int tx = threadIdx.x, ty = threadIdx.y;
  const int km = k0 + ty, n = n0 + tx;
  float v = (km < job.Ksrc && n < job.Nsrc) ? job.src[(size_t)km * job.Nsrc + n] : 0.f;
  t[ty][tx] = v;
  __syncthreads();
  if (k0 + tx < job.Kpad && n0 + ty < job.Npad)
    job.dst[(size_t)(n0 + ty) * job.ld + k0 + tx] = f2bf_u(t[tx][ty]);
}

// Split-bf16 stacked pack: W[Ktot][Nsrc] = [srcA(splitK); srcB]; k blocks [hi,hi,lo].
__global__ void k_pack_split(const float* __restrict__ srcA, const float* __restrict__ srcB,
                             int splitK, int Ktot, int Nsrc,
                             u16* __restrict__ dst, int dstLd) {
  __shared__ float t[16][17];
  const int k0 = blockIdx.x * 16, n0 = blockIdx.y * 16;
  const int tx = threadIdx.x, ty = threadIdx.y;
  int kOut = k0 + ty;
  int blk = kOut / Ktot; int km = kOut - blk * Ktot;
  const int n = n0 + tx;
  float v = 0.f;
  if (n < Nsrc)
    v = (km < splitK) ? srcA[(size_t)km * Nsrc + n]
                      : srcB[(size_t)(km - splitK) * Nsrc + n];
  t[ty][tx] = v;
  __syncthreads();
  const int kw = k0 + tx;
  const int blkw = kw / Ktot;
  float x = t[tx][ty];
  u16 hb = f2bf_u(x);
  u16 o = (blkw == 2) ? f2bf_u(x - bf2f_u(hb)) : hb;
  dst[(size_t)(n0 + ty) * dstLd + kw] = o;
}

// ---------------- SAGE aggregation (atomic-free per-node scan) -------------
__global__ void k_aggpack1(const int* __restrict__ es, const int* __restrict__ ed,
                           const float* __restrict__ nodes, u16* __restrict__ Agp) {
  const int node = blockIdx.x;              // 0..383
  const int c = threadIdx.x * 2;
  u16* row = Agp + (size_t)node * 3072;
  if (node >= 360) {
#pragma unroll
    for (int b = 0; b < 3; ++b) { row[b * 1024 + c] = 0; row[b * 1024 + c + 1] = 0;
                                  row[b * 1024 + 512 + c] = 0; row[b * 1024 + 512 + c + 1] = 0; }
    return;
  }
  float a0 = 0.f, a1 = 0.f, cnt = 0.f;
  for (int e = 0; e < 1262; ++e) {
    if (ed[e] == node) {
      const float* xr = nodes + (size_t)es[e] * 512;
      a0 += xr[c]; a1 += xr[c + 1]; cnt += 1.f;
    }
  }
  float inv = 1.f / fmaxf(cnt, 1.f);
  a0 *= inv; a1 *= inv;
  float x0 = nodes[(size_t)node * 512 + c], x1 = nodes[(size_t)node * 512 + c + 1];
  u16 ah0 = f2bf_u(a0), ah1 = f2bf_u(a1);
  u16 al0 = f2bf_u(a0 - bf2f_u(ah0)), al1 = f2bf_u(a1 - bf2f_u(ah1));
  u16 xh0 = f2bf_u(x0), xh1 = f2bf_u(x1);
  u16 xl0 = f2bf_u(x0 - bf2f_u(xh0)), xl1 = f2bf_u(x1 - bf2f_u(xh1));
  row[c] = ah0; row[c + 1] = ah1; row[512 + c] = xh0; row[512 + c + 1] = xh1;
  row[1024 + c] = al0; row[1024 + c + 1] = al1; row[1536 + c] = xl0; row[1536 + c + 1] = xl1;
  row[2048 + c] = ah0; row[2048 + c + 1] = ah1; row[2560 + c] = xh0; row[2560 + c + 1] = xh1;
}

__global__ void k_aggpack2(const int* __restrict__ es, const int* __restrict__ ed,
                           const float* __restrict__ Hf, u16* __restrict__ A2p) {
  const int node = blockIdx.x;              // 0..383
  const int c = threadIdx.x * 8;
  u16* row = A2p + (size_t)node * 12288;
  if (node >= 360) {
#pragma unroll
    for (int b = 0; b < 3; ++b)
      for (int j = 0; j < 8; ++j) { row[b * 4096 + c + j] = 0; row[b * 4096 + 2048 + c + j] = 0; }
    return;
  }
  float a[8] = {}; float cnt = 0.f;
  for (int e = 0; e < 1262; ++e) {
    if (ed[e] == node) {
      const float* hr = Hf + (size_t)es[e] * 2048 + c;
      float4 v0 = *(const float4*)hr, v1 = *(const float4*)(hr + 4);
      a[0] += v0.x; a[1] += v0.y; a[2] += v0.z; a[3] += v0.w;
      a[4] += v1.x; a[5] += v1.y; a[6] += v1.z; a[7] += v1.w;
      cnt += 1.f;
    }
  }
  float inv = 1.f / fmaxf(cnt, 1.f);
  const float* hx = Hf + (size_t)node * 2048 + c;
#pragma unroll
  for (int j = 0; j < 8; ++j) {
    float av = a[j] * inv, xv = hx[j];
    u16 ah = f2bf_u(av), xh = f2bf_u(xv);
    u16 al = f2bf_u(av - bf2f_u(ah)), xl = f2bf_u(xv - bf2f_u(xh));
    row[c + j] = ah; row[2048 + c + j] = xh;
    row[4096 + c + j] = al; row[6144 + c + j] = xl;
    row[8192 + c + j] = ah; row[10240 + c + j] = xh;
  }
}

// partial-sum + bias kernels
__global__ void k_relu_bias_f32(const float* __restrict__ acc, const float* __restrict__ bias,
                                float* __restrict__ out, int N, int total, int nz, int zs) {
  int idx = blockIdx.x * 256 + threadIdx.x;
  if (idx >= total) return;
  float s = 0.f;
  for (int z = 0; z < nz; ++z) s += acc[(size_t)z * zs + idx];
  out[idx] = fmaxf(s + bias[idx % N], 0.f);
}
__global__ void k_bias_bf16(const float* __restrict__ acc, const float* __restrict__ bias,
                            u16* __restrict__ out, int N, int total, int nz, int zs) {
  int idx = blockIdx.x * 256 + threadIdx.x;
  if (idx >= total) return;
  float s = 0.f;
  for (int z = 0; z < nz; ++z) s += acc[(size_t)z * zs + idx];
  out[idx] = f2bf_u(s + bias[idx % N]);
}

__global__ void k_cvt_bf16(const float* __restrict__ src, u16* __restrict__ dst, int n4) {
  int idx = blockIdx.x * 256 + threadIdx.x;
  if (idx >= n4) return;
  float4 v = *(const float4*)(src + ((size_t)idx << 2));
  ushort4 o;
  o.x = f2bf_u(v.x); o.y = f2bf_u(v.y); o.z = f2bf_u(v.z); o.w = f2bf_u(v.w);
  *(ushort4*)(dst + ((size_t)idx << 2)) = o;
}

// H1[r][c<1000] = relu(F[a(r)][c] + G[115+o(r)][c] + bp1[c]); pad 0 to 1024.
// T1[rt][c<800] = relu(I1[rt][c] + bi1[c]); pad 0 to 832.
__global__ void k_buildH1T1(const float* __restrict__ Facc,
                            const int* __restrict__ t_attr, const int* __restrict__ obj,
                            const int* __restrict__ negat, const float* __restrict__ bp1,
                            const float* __restrict__ bi1,
                            u16* __restrict__ H1, u16* __restrict__ T1) {
  int idx = blockIdx.x * 256 + threadIdx.x;
  if (idx >= 29696 * 128) return;
  int r = idx >> 7, ch = idx & 127, c = ch << 3;
  if (r < 29440) {
    u16* dst = H1 + ((size_t)r << 10) + c;
    if (c >= 1000) { ushort4 z = {0,0,0,0}; *(ushort4*)dst = z; *(ushort4*)(dst + 4) = z; return; }
    int a, o;
    if (r < 256) { a = t_attr[r]; o = obj[r]; }
    else { int rr = r - 256; a = negat[rr]; o = obj[rr / 114]; }
    const float* Fa = Facc + (size_t)a * 4096 + c;
    const float* Go = Facc + (size_t)(115 + o) * 4096 + 1024 + c;
    const float* Bp = bp1 + c;
    ushort4 o0, o1;
    float4 f0 = *(const float4*)Fa, f1 = *(const float4*)(Fa + 4);
    float4 g0 = *(const float4*)Go, g1 = *(const float4*)(Go + 4);
    float4 b0 = *(const float4*)Bp, b1 = *(const float4*)(Bp + 4);
    o0.x = f2bf_u(fmaxf(f0.x + g0.x + b0.x, 0.f));
    o0.y = f2bf_u(fmaxf(f0.y + g0.y + b0.y, 0.f));
    o0.z = f2bf_u(fmaxf(f0.z + g0.z + b0.z, 0.f));
    o0.w = f2bf_u(fmaxf(f0.w + g0.w + b0.w, 0.f));
    o1.x = f2bf_u(fmaxf(f1.x + g1.x + b1.x, 0.f));
    o1.y = f2bf_u(fmaxf(f1.y + g1.y + b1.y, 0.f));
    o1.z = f2bf_u(fmaxf(f1.z + g1.z + b1.z, 0.f));
    o1.w = f2bf_u(fmaxf(f1.w + g1.w + b1.w, 0.f));
    *(ushort4*)dst = o0; *(ushort4*)(dst + 4) = o1;
  } else {
    int rt = r - 29440;
    if (ch >= 104) return;
    u16* dst = T1 + (size_t)rt * 832 + c;
    if (c >= 800) { ushort4 z = {0,0,0,0}; *(ushort4*)dst = z; *(ushort4*)(dst + 4) = z; return; }
    const float* I1 = Facc + (size_t)(384 + rt) * 4096 + 2048 + c;
    const float* Bi = bi1 + c;
    float4 f0 = *(const float4*)I1, f1 = *(const float4*)(I1 + 4);
    float4 b0 = *(const float4*)Bi, b1 = *(const float4*)(Bi + 4);
    ushort4 o0, o1;
    o0.x = f2bf_u(fmaxf(f0.x + b0.x, 0.f)); o0.y = f2bf_u(fmaxf(f0.y + b0.y, 0.f));
    o0.z = f2bf_u(fmaxf(f0.z + b0.z, 0.f)); o0.w = f2bf_u(fmaxf(f0.w + b0.w, 0.f));
    o1.x = f2bf_u(fmaxf(f1.x + b1.x, 0.f)); o1.y = f2bf_u(fmaxf(f1.y + b1.y, 0.f));
    o1.z = f2bf_u(fmaxf(f1.z + b1.z, 0.f)); o1.w = f2bf_u(fmaxf(f1.w + b1.w, 0.f));
    *(ushort4*)dst = o0; *(ushort4*)(dst + 4) = o1;
  }
}

// reduce 16 partials -> rs = rsqrt(sum)
__global__ void k_rs(const float* __restrict__ part, int nrows, float* __restrict__ rs) {
  int idx = blockIdx.x * 256 + threadIdx.x;
  if (idx >= nrows) return;
  float s = 0.f;
#pragma unroll
  for (int i = 0; i < 16; ++i) s += part[(size_t)i * nrows + idx];
  rs[idx] = rsqrtf(fmaxf(s, 1e-24f));
}

// scale the three f32 output regions by rsC
__global__ void k_norm3(float* __restrict__ cTheta, float* __restrict__ cNeg,
                        float* __restrict__ cTgt, const float* __restrict__ rsC) {
  int r = blockIdx.x;
  float s = rsC[r];
  float* row = (r < 256) ? cTheta + (size_t)r * 800
             : (r < 29440) ? cNeg + (size_t)(r - 256) * 800
                           : cTgt + (size_t)(r - 29440) * 800;
  int c = threadIdx.x;
  if (c < 200) {
    float4 v = *(float4*)(row + (c << 2));
    v.x *= s; v.y *= s; v.z *= s; v.w *= s;
    *(float4*)(row + (c << 2)) = v;
  }
}

// ---------------------------------------------------------------------------
extern "C" void kernel_launch(void* const* d_in, const int* in_sizes, int n_in,
                              void* d_out, int out_size, void* d_ws, size_t ws_size,
                              hipStream_t stream) {
  const float* nodes = (const float*)d_in[0];
  const float* s_img = (const float*)d_in[1];
  const float* t_img = (const float*)d_in[2];
  const float* Wl1 = (const float*)d_in[3];
  const float* Wr1 = (const float*)d_in[4];
  const float* b1  = (const float*)d_in[5];
  const float* Wl2 = (const float*)d_in[6];
  const float* Wr2 = (const float*)d_in[7];
  const float* b2  = (const float*)d_in[8];
  const float* Wp1 = (const float*)d_in[9];
  const float* bp1 = (const float*)d_in[10];
  const float* Wp2 = (const float*)d_in[11];
  const float* bp2 = (const float*)d_in[12];
  const float* Wi1 = (const float*)d_in[13];
  const float* bi1 = (const float*)d_in[14];
  const float* Wi2 = (const float*)d_in[15];
  const float* bi2 = (const float*)d_in[16];
  const float* Wi3 = (const float*)d_in[17];
  const float* bi3 = (const float*)d_in[18];
  const float* Wc1 = (const float*)d_in[19];
  const float* bc1 = (const float*)d_in[20];
  const float* Wc2 = (const float*)d_in[21];
  const float* bc2 = (const float*)d_in[22];
  const float* Wc3 = (const float*)d_in[23];
  const float* bc3 = (const float*)d_in[24];
  const int* e_src = (const int*)d_in[25];
  const int* e_dst = (const int*)d_in[26];
  const int* t_attr = (const int*)d_in[27];
  const int* obj    = (const int*)d_in[28];
  const int* negat  = (const int*)d_in[29];
  (void)in_sizes; (void)n_in; (void)out_size; (void)ws_size;

  float* out = (float*)d_out;
  float* cTheta = out;
  float* cTgt = out + 204800;
  float* cNeg = out + 409600;

  char* p = (char*)d_ws;
  auto alloc = [&](size_t bytes) -> void* {
    char* r = p; p += (bytes + 255) & ~(size_t)255; return (void*)r;
  };
  u16* W1t   = (u16*)alloc(2048ull * 3072 * 2);
  u16* W2t   = (u16*)alloc(512ull * 12288 * 2);
  u16* Wp2t  = (u16*)alloc(1024ull * 1024 * 2);
  u16* Wc1bt = (u16*)alloc(1024ull * 832 * 2);
  u16* Wc2t  = (u16*)alloc(1024ull * 896 * 2);
  u16* Wc3t  = (u16*)alloc(1024ull * 1024 * 2);
  u16* Wi2t  = (u16*)alloc(1024ull * 832 * 2);
  u16* Wi3t  = (u16*)alloc(1024ull * 1024 * 2);
  u16* Wcat  = (u16*)alloc(4096ull * 512 * 2);
  u16* Agp   = (u16*)alloc(384ull * 3072 * 2);
  float* Hacc = (float*)alloc(4ull * 384 * 2048 * 4);
  float* Hf   = (float*)alloc(384ull * 2048 * 4);
  u16* A2p   = (u16*)alloc(384ull * 12288 * 2);
  float* Zacc = (float*)alloc(8ull * 384 * 512 * 4);
  u16* A_cat = (u16*)alloc(896ull * 512 * 2);
  float* Facc = (float*)alloc(896ull * 4096 * 4);
  u16* T1    = (u16*)alloc(256ull * 832 * 2);
  u16* T2    = (u16*)alloc(256ull * 1024 * 2);
  float* rsqP16 = (float*)alloc(16ull * 29440 * 4);
  float* rsqC16 = (float*)alloc(16ull * 29696 * 4);
  float* rsP = (float*)alloc(29440ull * 4);
  float* rsC = (float*)alloc(29696ull * 4);
  u16* H1 = (u16*)alloc(29440ull * 1024 * 2);
  u16* X  = (u16*)alloc(29440ull * 832 * 2);
  u16* H3 = (u16*)alloc(29440ull * 1024 * 2);
  u16* H2 = H1;   // [29440][896] aliases H1 (dead after D2)

  dim3 tb(16, 16);
  k_pack_split<<<dim3(192, 128), tb, 0, stream>>>(Wl1, Wr1, 512, 1024, 2048, W1t, 3072);
  k_pack_split<<<dim3(768, 32), tb, 0, stream>>>(Wl2, Wr2, 2048, 4096, 512, W2t, 12288);
  {
    PJobs J;
    J.j[0] = {Wp2, Wp2t, 1000, 800, 1024, 1024, 1024};
    J.j[1] = {Wc1 + 512 * 800, Wc1bt, 800, 800, 832, 1024, 832};
    J.j[2] = {Wc2, Wc2t, 800, 1000, 896, 1024, 896};
    J.j[3] = {Wc3, Wc3t, 1000, 800, 1024, 1024, 1024};
    J.j[4] = {Wi2, Wi2t, 800, 1000, 832, 1024, 832};
    J.j[5] = {Wi3, Wi3t, 1000, 800, 1024, 1024, 1024};
    J.j[6] = {Wp1, Wcat, 512, 1000, 512, 1024, 512};
    J.j[7] = {Wp1 + 512 * 1000, Wcat + 1024 * 512, 512, 1000, 512, 1024, 512};
    J.j[8] = {Wi1, Wcat + 2048 * 512, 512, 800, 512, 1024, 512};
    J.j[9] = {Wc1, Wcat + 3072 * 512, 512, 800, 512, 1024, 512};
    k_pack10<<<dim3(64, 64, 10), tb, 0, stream>>>(J);
  }

  // SAGE
  k_aggpack1<<<dim3(384), 256, 0, stream>>>(e_src, e_dst, nodes, Agp);
  gemm_atom<0><<<dim3(16, 3, 4), 256, 0, stream>>>(Agp, 3072, W1t, 3072, 2048, 96, 24,
                                                   Hacc, 2048, 384 * 2048);
  k_relu_bias_f32<<<dim3(384 * 2048 / 256), 256, 0, stream>>>(Hacc, b1, Hf, 2048,
                                                              384 * 2048, 4, 384 * 2048);
  k_aggpack2<<<dim3(384), 256, 0, stream>>>(e_src, e_dst, Hf, A2p);
  gemm_atom<0><<<dim3(4, 3, 8), 256, 0, stream>>>(A2p, 12288, W2t, 12288, 512, 384, 48,
                                                  Zacc, 512, 384 * 512);
  k_bias_bf16<<<dim3(384 * 512 / 256), 256, 0, stream>>>(Zacc, b2, A_cat, 512,
                                                         384 * 512, 8, 384 * 512);
  k_cvt_bf16<<<dim3(128), 256, 0, stream>>>(t_img, A_cat + 384 * 512, 256 * 512 / 4);
  k_cvt_bf16<<<dim3(128), 256, 0, stream>>>(s_img, A_cat + 640 * 512, 256 * 512 / 4);

  // mega: [z | pad | t_img | s_img] @ [Wp1_top || Wp1_bot || Wi1 || Wc1_top]
  gemm_atom<1><<<dim3(32, 7, 1), 256, 0, stream>>>(A_cat, 512, Wcat, 512, 4096, 16, 16,
                                                   Facc, 4096, 0);
  k_buildH1T1<<<dim3(29696 * 128 / 256), 256, 0, stream>>>(Facc, t_attr, obj, negat,
                                                           bp1, bi1, H1, T1);

  // D2: pair_fc L2 -> X + rowsq partials  (K=1024 -> nK=32)
  {
    Panel s0{H1, 1024, Wp2t, 1024, bp2, 800, 832, 32, X, 832, nullptr, nullptr};
    gemm256<1><<<dim3(4, 115), 512, 0, stream>>>(s0, s0, 1 << 20, rsqP16, 29440,
                                                 nullptr, nullptr, nullptr);
  }
  k_rs<<<dim3(115), 256, 0, stream>>>(rsqP16, 29440, rsP);

  // D3: compo L1 (K=832 -> nK=26, rs-scale + S-gather) + img L2
  {
    Panel s0{X, 832, Wc1bt, 832, bc1, 800, 896, 26, H2, 896, rsP,
             Facc + 640 * 4096 + 3072};
    Panel s1{T1, 832, Wi2t, 832, bi2, 1000, 1024, 26, T2, 1024, nullptr, nullptr};
    gemm256<0><<<dim3(4, 116), 512, 0, stream>>>(s0, s1, 115, nullptr, 0,
                                                 nullptr, nullptr, nullptr);
  }
  // D4: compo L2 (K=896 -> nK=28)
  {
    Panel s0{H2, 896, Wc2t, 896, bc2, 1000, 1024, 28, H3, 1024, nullptr, nullptr};
    gemm256<0><<<dim3(4, 115), 512, 0, stream>>>(s0, s0, 1 << 20, nullptr, 0,
                                                 nullptr, nullptr, nullptr);
  }
  // D5: compo L3 (theta+neg) + img L3 (targets)  (K=1024 -> nK=32)
  {
    Panel s0{H3, 1024, Wc3t, 1024, bc3, 800, 800, 32, nullptr, 800, nullptr, nullptr};
    Panel s1{T2, 1024, Wi3t, 1024, bi3, 800, 800, 32, nullptr, 800, nullptr, nullptr};
    gemm256<3><<<dim3(4, 116), 512, 0, stream>>>(s0, s1, 115, rsqC16, 29696,
                                                 cTheta, cNeg, cTgt);
  }
  k_rs<<<dim3(116), 256, 0, stream>>>(rsqC16, 29696, rsC);
  k_norm3<<<dim3(29696), 256, 0, stream>>>(cTheta, cNeg, cTgt, rsC);
}

// Round 9
// 724.253 us; speedup vs baseline: 1.2393x; 1.2393x over previous
//
#include <hip/hip_runtime.h>

// ---------------------------------------------------------------------------
// GAE_IR_79499844649397. Atomic-free pipeline.
// Big GEMMs: 128x128 tile, 4 waves, BK=32, LDS 32KB dbuf + vmcnt(4),
// slot-XOR swizzle (conflict-free), __launch_bounds__(256,3) -> 3 blocks/CU
// (64 AGPR + capped VGPR <= 170). 1-D grid, XCD chunked swizzle, linear
// 2-panel decode. rowsq -> 14 partial slots + k_rs reduce.
// ---------------------------------------------------------------------------

typedef unsigned short u16;
typedef __bf16 bf16x8 __attribute__((ext_vector_type(8)));
typedef float f32x4 __attribute__((ext_vector_type(4)));

__device__ inline u16 f2bf_u(float f) {
  union { float f; unsigned u; } a; a.f = f;
  unsigned u = a.u + 0x7fffu + ((a.u >> 16) & 1u);   // RNE
  return (u16)(u >> 16);
}
__device__ inline float bf2f_u(u16 h) {
  union { unsigned u; float f; } a; a.u = ((unsigned)h) << 16; return a.f;
}

#define GLOAD16(gptr, lptr)                                                   \
  __builtin_amdgcn_global_load_lds(                                           \
      (__attribute__((address_space(1))) void*)(gptr),                        \
      (__attribute__((address_space(3))) void*)(lptr), 16, 0, 0)

#define BAR  __builtin_amdgcn_s_barrier()
#define LGKM0 asm volatile("s_waitcnt lgkmcnt(0)" ::: "memory")
#define VMC4 asm volatile("s_waitcnt vmcnt(4)" ::: "memory")
#define VMC0 asm volatile("s_waitcnt vmcnt(0)" ::: "memory")

struct Panel {
  const u16* A; int lda;
  const u16* B; int ldb;
  const float* bias; int biasN;
  int N; int nK;               // nK in units of 32
  void* out; int ldc;
  const float* rsVec;          // optional per-row scale (pre-rsqrt'd)
  const float* addS;           // optional gathered row-add (f32, ld 4096)
  int gx;                      // col-blocks (N tiles of 128)
  int rowG0;                   // global row offset of this panel
};

// MODE 0: bf16 out, v = relu(acc*rs + bias + S[b])
// MODE 1: bf16 out + bias, + rowsq partials
// MODE 3: f32 out + bias, 3-range remap + rowsq partials
template <int MODE>
__global__ __launch_bounds__(256, 3) void gemm128(
    Panel p0, Panel p1, int c0,
    float* __restrict__ rsPart, int rsLd,
    float* __restrict__ cTheta, float* __restrict__ cNeg, float* __restrict__ cTgt) {
  __shared__ u16 As[2][4096];   // [128][32] x2
  __shared__ u16 Bs[2][4096];

  // chunked-bijective XCD swizzle (1-D grid)
  const int nwg = gridDim.x;
  const int orig = blockIdx.x;
  const int q = nwg >> 3, r = nwg & 7, xcd = orig & 7;
  const int basewg = (xcd < r) ? xcd * (q + 1) : r * (q + 1) + (xcd - r) * q;
  const int wg = basewg + (orig >> 3);

  Panel P; int pby, pbx;
  if (wg < c0) { P = p0; pby = wg / p0.gx; pbx = wg - pby * p0.gx; }
  else { P = p1; const int w2 = wg - c0; pby = w2 / p1.gx; pbx = w2 - pby * p1.gx; }
  const int m0 = pby << 7, n0 = pbx << 7;

  const int tid = threadIdx.x;
  const int wave = tid >> 6, lane = tid & 63;
  const int lr = lane & 15, lg = lane >> 4;
  const int wr = wave >> 1, wc = wave & 1;

  f32x4 acc[4][4] = {};

  // staging with slot-XOR swizzle: LDS[row][sc] = G[row][sc ^ ((row>>1)&3)]
  const int r0 = tid >> 2, sc0 = tid & 3;
  const size_t aOff  = (size_t)(m0 + r0) * P.lda + ((sc0 ^ ((r0 >> 1) & 3)) << 3);
  const size_t aOff1 = (size_t)(m0 + r0 + 64) * P.lda + ((sc0 ^ (((r0 + 64) >> 1) & 3)) << 3);
  const size_t bOff  = (size_t)(n0 + r0) * P.ldb + ((sc0 ^ ((r0 >> 1) & 3)) << 3);
  const size_t bOff1 = (size_t)(n0 + r0 + 64) * P.ldb + ((sc0 ^ (((r0 + 64) >> 1) & 3)) << 3);
  const int lL = (r0 * 4 + sc0) << 4;   // byte offset within buffer (linear dest)

  auto stage = [&](int kt, int b) {
    const int k0 = kt << 5;
    GLOAD16(P.A + aOff + k0, (char*)As[b] + lL);
    GLOAD16(P.A + aOff1 + k0, (char*)As[b] + lL + 4096);
    GLOAD16(P.B + bOff + k0, (char*)Bs[b] + lL);
    GLOAD16(P.B + bOff1 + k0, (char*)Bs[b] + lL + 4096);
  };

  const int nK = P.nK;
  stage(0, 0);
  for (int kt = 0; kt < nK; ++kt) {
    const int cb = kt & 1;
    if (kt + 1 < nK) { stage(kt + 1, cb ^ 1); VMC4; }
    else { VMC0; }
    BAR;

    bf16x8 af[4], bv[4];
#pragma unroll
    for (int m = 0; m < 4; ++m) {
      const int row = (wr << 6) + (m << 4) + lr;
      af[m] = *(const bf16x8*)(&As[cb][row * 32 + ((lg ^ ((row >> 1) & 3)) << 3)]);
    }
#pragma unroll
    for (int n = 0; n < 4; ++n) {
      const int row = (wc << 6) + (n << 4) + lr;
      bv[n] = *(const bf16x8*)(&Bs[cb][row * 32 + ((lg ^ ((row >> 1) & 3)) << 3)]);
    }
#pragma unroll
    for (int m = 0; m < 4; ++m)
#pragma unroll
      for (int n = 0; n < 4; ++n)
        acc[m][n] = __builtin_amdgcn_mfma_f32_16x16x32_bf16(af[m], bv[n], acc[m][n], 0, 0, 0);

    LGKM0;
    BAR;
  }

  const int gcb = n0 + (wc << 6);
  const int grb = m0 + (wr << 6) + (lg << 2);
#pragma unroll
  for (int m = 0; m < 4; ++m) {
#pragma unroll
    for (int rr = 0; rr < 4; ++rr) {
      const int grow = grb + (m << 4) + rr;
      const int growG = P.rowG0 + grow;
      float ss = 0.f;
      float rs = 1.f;
      const float* Sp = nullptr;
      if (MODE == 0) {
        if (P.rsVec) rs = P.rsVec[growG];
        if (P.addS) {
          int bv2 = (growG < 256) ? growG : (growG - 256) / 114;
          Sp = P.addS + (size_t)bv2 * 4096;
        }
      }
#pragma unroll
      for (int n = 0; n < 4; ++n) {
        const int gc = gcb + (n << 4) + lr;
        if (gc >= P.N) continue;
        float v = acc[m][n][rr];
        if (MODE == 0) {
          v *= rs;
          if (gc < P.biasN) v += P.bias[gc];
          if (Sp) v += Sp[gc];
          v = fmaxf(v, 0.f);
          ((u16*)P.out)[(size_t)grow * P.ldc + gc] = f2bf_u(v);
        } else if (MODE == 1) {
          if (gc < P.biasN) v += P.bias[gc];
          ((u16*)P.out)[(size_t)grow * P.ldc + gc] = f2bf_u(v);
          ss += v * v;
        } else {
          if (gc < P.biasN) v += P.bias[gc];
          float* op = (growG < 256) ? cTheta + (size_t)growG * 800
                    : (growG < 29440) ? cNeg + (size_t)(growG - 256) * 800
                                      : cTgt + (size_t)(growG - 29440) * 800;
          op[gc] = v;
          ss += v * v;
        }
      }
      if (MODE == 1 || MODE == 3) {
        ss += __shfl_xor(ss, 1); ss += __shfl_xor(ss, 2);
        ss += __shfl_xor(ss, 4); ss += __shfl_xor(ss, 8);
        if (lr == 0) rsPart[(size_t)((pbx << 1) + wc) * rsLd + growG] = ss;
      }
    }
  }
}

// ---------------------------------------------------------------------------
// Small-M GEMM: 128x128, BK=32. STORE=1 plain store; else z-partial store.
// ---------------------------------------------------------------------------
template <int STORE>
__global__ __launch_bounds__(256) void gemm_atom(
    const u16* __restrict__ A, int lda, const u16* __restrict__ Bt, int ldb,
    int N, int nK, int ktChunk, float* __restrict__ Cf, int ldc, int zStride) {
  __shared__ u16 As[2][4096];
  __shared__ u16 Bs[2][4096];
  const int tid = threadIdx.x;
  const int wave = tid >> 6, lane = tid & 63;
  const int lr = lane & 15, lg = lane >> 4;
  const int wr = wave >> 1, wc = wave & 1;
  const int m0 = blockIdx.y << 7, n0 = blockIdx.x << 7;

  f32x4 acc[4][4] = {};

  const size_t aOff  = (size_t)(m0 + (tid >> 2)) * lda + ((tid & 3) << 3);
  const size_t aOff1 = aOff + (size_t)64 * lda;
  const size_t bOff  = (size_t)(n0 + (tid >> 2)) * ldb + ((tid & 3) << 3);
  const size_t bOff1 = bOff + (size_t)64 * ldb;

  const int kt0 = blockIdx.z * ktChunk;
  int ktEnd = kt0 + ktChunk; if (ktEnd > nK) ktEnd = nK;

  auto stage = [&](int kt, int b) {
    const int k0 = kt << 5;
    u16* Ad = &As[b][wave << 9];
    u16* Bd = &Bs[b][wave << 9];
    GLOAD16(A + aOff + k0, Ad);
    GLOAD16(A + aOff1 + k0, Ad + 2048);
    GLOAD16(Bt + bOff + k0, Bd);
    GLOAD16(Bt + bOff1 + k0, Bd + 2048);
  };

  if (kt0 < ktEnd) stage(kt0, 0);
  for (int kt = kt0; kt < ktEnd; ++kt) {
    const int cb = (kt - kt0) & 1;
    if (kt + 1 < ktEnd) {
      stage(kt + 1, cb ^ 1);
      VMC4;
    } else {
      VMC0;
    }
    BAR;
    asm volatile("" ::: "memory");

    bf16x8 af[4], bvv[4];
#pragma unroll
    for (int m = 0; m < 4; ++m)
      af[m] = *(const bf16x8*)(&As[cb][(((wr << 6) + (m << 4) + lr) << 5) + (lg << 3)]);
#pragma unroll
    for (int n = 0; n < 4; ++n)
      bvv[n] = *(const bf16x8*)(&Bs[cb][(((wc << 6) + (n << 4) + lr) << 5) + (lg << 3)]);
#pragma unroll
    for (int m = 0; m < 4; ++m)
#pragma unroll
      for (int n = 0; n < 4; ++n)
        acc[m][n] = __builtin_amdgcn_mfma_f32_16x16x32_bf16(af[m], bvv[n], acc[m][n], 0, 0, 0);

    asm volatile("s_waitcnt lgkmcnt(0)" ::: "memory");
    BAR;
    asm volatile("" ::: "memory");
  }

  float* out = STORE ? Cf : (Cf + (size_t)blockIdx.z * zStride);
  const int gcb = n0 + (wc << 6);
  const int grb = m0 + (wr << 6) + (lg << 2);
#pragma unroll
  for (int m = 0; m < 4; ++m)
#pragma unroll
    for (int rr = 0; rr < 4; ++rr) {
      const int grow = grb + (m << 4) + rr;
#pragma unroll
      for (int n = 0; n < 4; ++n) {
        const int gc = gcb + (n << 4) + lr;
        if (gc < N) out[(size_t)grow * ldc + gc] = acc[m][n][rr];
      }
    }
}

// --------------------------- weight packing --------------------------------
struct PJob { const float* src; u16* dst; int Ksrc, Nsrc, Kpad, Npad, ld; };
struct PJobs { PJob j[10]; };

__global__ void k_pack10(PJobs J) {
  PJob job = J.j[blockIdx.z];
  const int k0 = blockIdx.x * 16, n0 = blockIdx.y * 16;
  if (k0 >= job.Kpad || n0 >= job.Npad) return;
  __shared__ float t[16][17];
  const int tx = threadIdx.x, ty = threadIdx.y;
  const int km = k0 + ty, n = n0 + tx;
  float v = (km < job.Ksrc && n < job.Nsrc) ? job.src[(size_t)km * job.Nsrc + n] : 0.f;
  t[ty][tx] = v;
  __syncthreads();
  if (k0 + tx < job.Kpad && n0 + ty < job.Npad)
    job.dst[(size_t)(n0 + ty) * job.ld + k0 + tx] = f2bf_u(t[tx][ty]);
}

// Split-bf16 stacked pack: W[Ktot][Nsrc] = [srcA(splitK); srcB]; k blocks [hi,hi,lo].
__global__ void k_pack_split(const float* __restrict__ srcA, const float* __restrict__ srcB,
                             int splitK, int Ktot, int Nsrc,
                             u16* __restrict__ dst, int dstLd) {
  __shared__ float t[16][17];
  const int k0 = blockIdx.x * 16, n0 = blockIdx.y * 16;
  const int tx = threadIdx.x, ty = threadIdx.y;
  int kOut = k0 + ty;
  int blk = kOut / Ktot; int km = kOut - blk * Ktot;
  const int n = n0 + tx;
  float v = 0.f;
  if (n < Nsrc)
    v = (km < splitK) ? srcA[(size_t)km * Nsrc + n]
                      : srcB[(size_t)(km - splitK) * Nsrc + n];
  t[ty][tx] = v;
  __syncthreads();
  const int kw = k0 + tx;
  const int blkw = kw / Ktot;
  float x = t[tx][ty];
  u16 hb = f2bf_u(x);
  u16 o = (blkw == 2) ? f2bf_u(x - bf2f_u(hb)) : hb;
  dst[(size_t)(n0 + ty) * dstLd + kw] = o;
}

// ---------------- SAGE aggregation (atomic-free per-node scan) -------------
__global__ void k_aggpack1(const int* __restrict__ es, const int* __restrict__ ed,
                           const float* __restrict__ nodes, u16* __restrict__ Agp) {
  const int node = blockIdx.x;              // 0..383
  const int c = threadIdx.x * 2;
  u16* row = Agp + (size_t)node * 3072;
  if (node >= 360) {
#pragma unroll
    for (int b = 0; b < 3; ++b) { row[b * 1024 + c] = 0; row[b * 1024 + c + 1] = 0;
                                  row[b * 1024 + 512 + c] = 0; row[b * 1024 + 512 + c + 1] = 0; }
    return;
  }
  float a0 = 0.f, a1 = 0.f, cnt = 0.f;
  for (int e = 0; e < 1262; ++e) {
    if (ed[e] == node) {
      const float* xr = nodes + (size_t)es[e] * 512;
      a0 += xr[c]; a1 += xr[c + 1]; cnt += 1.f;
    }
  }
  float inv = 1.f / fmaxf(cnt, 1.f);
  a0 *= inv; a1 *= inv;
  float x0 = nodes[(size_t)node * 512 + c], x1 = nodes[(size_t)node * 512 + c + 1];
  u16 ah0 = f2bf_u(a0), ah1 = f2bf_u(a1);
  u16 al0 = f2bf_u(a0 - bf2f_u(ah0)), al1 = f2bf_u(a1 - bf2f_u(ah1));
  u16 xh0 = f2bf_u(x0), xh1 = f2bf_u(x1);
  u16 xl0 = f2bf_u(x0 - bf2f_u(xh0)), xl1 = f2bf_u(x1 - bf2f_u(xh1));
  row[c] = ah0; row[c + 1] = ah1; row[512 + c] = xh0; row[512 + c + 1] = xh1;
  row[1024 + c] = al0; row[1024 + c + 1] = al1; row[1536 + c] = xl0; row[1536 + c + 1] = xl1;
  row[2048 + c] = ah0; row[2048 + c + 1] = ah1; row[2560 + c] = xh0; row[2560 + c + 1] = xh1;
}

__global__ void k_aggpack2(const int* __restrict__ es, const int* __restrict__ ed,
                           const float* __restrict__ Hf, u16* __restrict__ A2p) {
  const int node = blockIdx.x;              // 0..383
  const int c = threadIdx.x * 8;
  u16* row = A2p + (size_t)node * 12288;
  if (node >= 360) {
#pragma unroll
    for (int b = 0; b < 3; ++b)
      for (int j = 0; j < 8; ++j) { row[b * 4096 + c + j] = 0; row[b * 4096 + 2048 + c + j] = 0; }
    return;
  }
  float a[8] = {}; float cnt = 0.f;
  for (int e = 0; e < 1262; ++e) {
    if (ed[e] == node) {
      const float* hr = Hf + (size_t)es[e] * 2048 + c;
      float4 v0 = *(const float4*)hr, v1 = *(const float4*)(hr + 4);
      a[0] += v0.x; a[1] += v0.y; a[2] += v0.z; a[3] += v0.w;
      a[4] += v1.x; a[5] += v1.y; a[6] += v1.z; a[7] += v1.w;
      cnt += 1.f;
    }
  }
  float inv = 1.f / fmaxf(cnt, 1.f);
  const float* hx = Hf + (size_t)node * 2048 + c;
#pragma unroll
  for (int j = 0; j < 8; ++j) {
    float av = a[j] * inv, xv = hx[j];
    u16 ah = f2bf_u(av), xh = f2bf_u(xv);
    u16 al = f2bf_u(av - bf2f_u(ah)), xl = f2bf_u(xv - bf2f_u(xh));
    row[c + j] = ah; row[2048 + c + j] = xh;
    row[4096 + c + j] = al; row[6144 + c + j] = xl;
    row[8192 + c + j] = ah; row[10240 + c + j] = xh;
  }
}

// partial-sum + bias kernels
__global__ void k_relu_bias_f32(const float* __restrict__ acc, const float* __restrict__ bias,
                                float* __restrict__ out, int N, int total, int nz, int zs) {
  int idx = blockIdx.x * 256 + threadIdx.x;
  if (idx >= total) return;
  float s = 0.f;
  for (int z = 0; z < nz; ++z) s += acc[(size_t)z * zs + idx];
  out[idx] = fmaxf(s + bias[idx % N], 0.f);
}
__global__ void k_bias_bf16(const float* __restrict__ acc, const float* __restrict__ bias,
                            u16* __restrict__ out, int N, int total, int nz, int zs) {
  int idx = blockIdx.x * 256 + threadIdx.x;
  if (idx >= total) return;
  float s = 0.f;
  for (int z = 0; z < nz; ++z) s += acc[(size_t)z * zs + idx];
  out[idx] = f2bf_u(s + bias[idx % N]);
}

__global__ void k_cvt_bf16(const float* __restrict__ src, u16* __restrict__ dst, int n4) {
  int idx = blockIdx.x * 256 + threadIdx.x;
  if (idx >= n4) return;
  float4 v = *(const float4*)(src + ((size_t)idx << 2));
  ushort4 o;
  o.x = f2bf_u(v.x); o.y = f2bf_u(v.y); o.z = f2bf_u(v.z); o.w = f2bf_u(v.w);
  *(ushort4*)(dst + ((size_t)idx << 2)) = o;
}

// H1[r][c<1000] = relu(F[a(r)][c] + G[115+o(r)][c] + bp1[c]); pad 0 to 1024.
// T1[rt][c<800] = relu(I1[rt][c] + bi1[c]); pad 0 to 832.
__global__ void k_buildH1T1(const float* __restrict__ Facc,
                            const int* __restrict__ t_attr, const int* __restrict__ obj,
                            const int* __restrict__ negat, const float* __restrict__ bp1,
                            const float* __restrict__ bi1,
                            u16* __restrict__ H1, u16* __restrict__ T1) {
  int idx = blockIdx.x * 256 + threadIdx.x;
  if (idx >= 29696 * 128) return;
  int r = idx >> 7, ch = idx & 127, c = ch << 3;
  if (r < 29440) {
    u16* dst = H1 + ((size_t)r << 10) + c;
    if (c >= 1000) { ushort4 z = {0,0,0,0}; *(ushort4*)dst = z; *(ushort4*)(dst + 4) = z; return; }
    int a, o;
    if (r < 256) { a = t_attr[r]; o = obj[r]; }
    else { int rr = r - 256; a = negat[rr]; o = obj[rr / 114]; }
    const float* Fa = Facc + (size_t)a * 4096 + c;
    const float* Go = Facc + (size_t)(115 + o) * 4096 + 1024 + c;
    const float* Bp = bp1 + c;
    ushort4 o0, o1;
    float4 f0 = *(const float4*)Fa, f1 = *(const float4*)(Fa + 4);
    float4 g0 = *(const float4*)Go, g1 = *(const float4*)(Go + 4);
    float4 b0 = *(const float4*)Bp, b1 = *(const float4*)(Bp + 4);
    o0.x = f2bf_u(fmaxf(f0.x + g0.x + b0.x, 0.f));
    o0.y = f2bf_u(fmaxf(f0.y + g0.y + b0.y, 0.f));
    o0.z = f2bf_u(fmaxf(f0.z + g0.z + b0.z, 0.f));
    o0.w = f2bf_u(fmaxf(f0.w + g0.w + b0.w, 0.f));
    o1.x = f2bf_u(fmaxf(f1.x + g1.x + b1.x, 0.f));
    o1.y = f2bf_u(fmaxf(f1.y + g1.y + b1.y, 0.f));
    o1.z = f2bf_u(fmaxf(f1.z + g1.z + b1.z, 0.f));
    o1.w = f2bf_u(fmaxf(f1.w + g1.w + b1.w, 0.f));
    *(ushort4*)dst = o0; *(ushort4*)(dst + 4) = o1;
  } else {
    int rt = r - 29440;
    if (ch >= 104) return;
    u16* dst = T1 + (size_t)rt * 832 + c;
    if (c >= 800) { ushort4 z = {0,0,0,0}; *(ushort4*)dst = z; *(ushort4*)(dst + 4) = z; return; }
    const float* I1 = Facc + (size_t)(384 + rt) * 4096 + 2048 + c;
    const float* Bi = bi1 + c;
    float4 f0 = *(const float4*)I1, f1 = *(const float4*)(I1 + 4);
    float4 b0 = *(const float4*)Bi, b1 = *(const float4*)(Bi + 4);
    ushort4 o0, o1;
    o0.x = f2bf_u(fmaxf(f0.x + b0.x, 0.f)); o0.y = f2bf_u(fmaxf(f0.y + b0.y, 0.f));
    o0.z = f2bf_u(fmaxf(f0.z + b0.z, 0.f)); o0.w = f2bf_u(fmaxf(f0.w + b0.w, 0.f));
    o1.x = f2bf_u(fmaxf(f1.x + b1.x, 0.f)); o1.y = f2bf_u(fmaxf(f1.y + b1.y, 0.f));
    o1.z = f2bf_u(fmaxf(f1.z + b1.z, 0.f)); o1.w = f2bf_u(fmaxf(f1.w + b1.w, 0.f));
    *(ushort4*)dst = o0; *(ushort4*)(dst + 4) = o1;
  }
}

// reduce 14 partials -> rs = rsqrt(sum)
__global__ void k_rs(const float* __restrict__ part, int nrows, float* __restrict__ rs) {
  int idx = blockIdx.x * 256 + threadIdx.x;
  if (idx >= nrows) return;
  float s = 0.f;
#pragma unroll
  for (int i = 0; i < 14; ++i) s += part[(size_t)i * nrows + idx];
  rs[idx] = rsqrtf(fmaxf(s, 1e-24f));
}

// scale the three f32 output regions by rsC
__global__ void k_norm3(float* __restrict__ cTheta, float* __restrict__ cNeg,
                        float* __restrict__ cTgt, const float* __restrict__ rsC) {
  int r = blockIdx.x;
  float s = rsC[r];
  float* row = (r < 256) ? cTheta + (size_t)r * 800
             : (r < 29440) ? cNeg + (size_t)(r - 256) * 800
                           : cTgt + (size_t)(r - 29440) * 800;
  int c = threadIdx.x;
  if (c < 200) {
    float4 v = *(float4*)(row + (c << 2));
    v.x *= s; v.y *= s; v.z *= s; v.w *= s;
    *(float4*)(row + (c << 2)) = v;
  }
}

// ---------------------------------------------------------------------------
extern "C" void kernel_launch(void* const* d_in, const int* in_sizes, int n_in,
                              void* d_out, int out_size, void* d_ws, size_t ws_size,
                              hipStream_t stream) {
  const float* nodes = (const float*)d_in[0];
  const float* s_img = (const float*)d_in[1];
  const float* t_img = (const float*)d_in[2];
  const float* Wl1 = (const float*)d_in[3];
  const float* Wr1 = (const float*)d_in[4];
  const float* b1  = (const float*)d_in[5];
  const float* Wl2 = (const float*)d_in[6];
  const float* Wr2 = (const float*)d_in[7];
  const float* b2  = (const float*)d_in[8];
  const float* Wp1 = (const float*)d_in[9];
  const float* bp1 = (const float*)d_in[10];
  const float* Wp2 = (const float*)d_in[11];
  const float* bp2 = (const float*)d_in[12];
  const float* Wi1 = (const float*)d_in[13];
  const float* bi1 = (const float*)d_in[14];
  const float* Wi2 = (const float*)d_in[15];
  const float* bi2 = (const float*)d_in[16];
  const float* Wi3 = (const float*)d_in[17];
  const float* bi3 = (const float*)d_in[18];
  const float* Wc1 = (const float*)d_in[19];
  const float* bc1 = (const float*)d_in[20];
  const float* Wc2 = (const float*)d_in[21];
  const float* bc2 = (const float*)d_in[22];
  const float* Wc3 = (const float*)d_in[23];
  const float* bc3 = (const float*)d_in[24];
  const int* e_src = (const int*)d_in[25];
  const int* e_dst = (const int*)d_in[26];
  const int* t_attr = (const int*)d_in[27];
  const int* obj    = (const int*)d_in[28];
  const int* negat  = (const int*)d_in[29];
  (void)in_sizes; (void)n_in; (void)out_size; (void)ws_size;

  float* out = (float*)d_out;
  float* cTheta = out;
  float* cTgt = out + 204800;
  float* cNeg = out + 409600;

  char* p = (char*)d_ws;
  auto alloc = [&](size_t bytes) -> void* {
    char* r = p; p += (bytes + 255) & ~(size_t)255; return (void*)r;
  };
  u16* W1t   = (u16*)alloc(2048ull * 3072 * 2);
  u16* W2t   = (u16*)alloc(512ull * 12288 * 2);
  u16* Wp2t  = (u16*)alloc(1024ull * 1024 * 2);
  u16* Wc1bt = (u16*)alloc(1024ull * 832 * 2);
  u16* Wc2t  = (u16*)alloc(1024ull * 896 * 2);
  u16* Wc3t  = (u16*)alloc(1024ull * 1024 * 2);
  u16* Wi2t  = (u16*)alloc(1024ull * 832 * 2);
  u16* Wi3t  = (u16*)alloc(1024ull * 1024 * 2);
  u16* Wcat  = (u16*)alloc(4096ull * 512 * 2);
  u16* Agp   = (u16*)alloc(384ull * 3072 * 2);
  float* Hacc = (float*)alloc(4ull * 384 * 2048 * 4);
  float* Hf   = (float*)alloc(384ull * 2048 * 4);
  u16* A2p   = (u16*)alloc(384ull * 12288 * 2);
  float* Zacc = (float*)alloc(8ull * 384 * 512 * 4);
  u16* A_cat = (u16*)alloc(896ull * 512 * 2);
  float* Facc = (float*)alloc(896ull * 4096 * 4);
  u16* T1    = (u16*)alloc(256ull * 832 * 2);
  u16* T2    = (u16*)alloc(256ull * 1024 * 2);
  float* rsqP16 = (float*)alloc(16ull * 29440 * 4);
  float* rsqC16 = (float*)alloc(16ull * 29696 * 4);
  float* rsP = (float*)alloc(29440ull * 4);
  float* rsC = (float*)alloc(29696ull * 4);
  u16* H1 = (u16*)alloc(29440ull * 1024 * 2);
  u16* X  = (u16*)alloc(29440ull * 832 * 2);
  u16* H3 = (u16*)alloc(29440ull * 1024 * 2);
  u16* H2 = H1;   // [29440][896] aliases H1 (dead after D2)

  dim3 tb(16, 16);
  k_pack_split<<<dim3(192, 128), tb, 0, stream>>>(Wl1, Wr1, 512, 1024, 2048, W1t, 3072);
  k_pack_split<<<dim3(768, 32), tb, 0, stream>>>(Wl2, Wr2, 2048, 4096, 512, W2t, 12288);
  {
    PJobs J;
    J.j[0] = {Wp2, Wp2t, 1000, 800, 1024, 1024, 1024};
    J.j[1] = {Wc1 + 512 * 800, Wc1bt, 800, 800, 832, 1024, 832};
    J.j[2] = {Wc2, Wc2t, 800, 1000, 896, 1024, 896};
    J.j[3] = {Wc3, Wc3t, 1000, 800, 1024, 1024, 1024};
    J.j[4] = {Wi2, Wi2t, 800, 1000, 832, 1024, 832};
    J.j[5] = {Wi3, Wi3t, 1000, 800, 1024, 1024, 1024};
    J.j[6] = {Wp1, Wcat, 512, 1000, 512, 1024, 512};
    J.j[7] = {Wp1 + 512 * 1000, Wcat + 1024 * 512, 512, 1000, 512, 1024, 512};
    J.j[8] = {Wi1, Wcat + 2048 * 512, 512, 800, 512, 1024, 512};
    J.j[9] = {Wc1, Wcat + 3072 * 512, 512, 800, 512, 1024, 512};
    k_pack10<<<dim3(64, 64, 10), tb, 0, stream>>>(J);
  }

  // SAGE
  k_aggpack1<<<dim3(384), 256, 0, stream>>>(e_src, e_dst, nodes, Agp);
  gemm_atom<0><<<dim3(16, 3, 4), 256, 0, stream>>>(Agp, 3072, W1t, 3072, 2048, 96, 24,
                                                   Hacc, 2048, 384 * 2048);
  k_relu_bias_f32<<<dim3(384 * 2048 / 256), 256, 0, stream>>>(Hacc, b1, Hf, 2048,
                                                              384 * 2048, 4, 384 * 2048);
  k_aggpack2<<<dim3(384), 256, 0, stream>>>(e_src, e_dst, Hf, A2p);
  gemm_atom<0><<<dim3(4, 3, 8), 256, 0, stream>>>(A2p, 12288, W2t, 12288, 512, 384, 48,
                                                  Zacc, 512, 384 * 512);
  k_bias_bf16<<<dim3(384 * 512 / 256), 256, 0, stream>>>(Zacc, b2, A_cat, 512,
                                                         384 * 512, 8, 384 * 512);
  k_cvt_bf16<<<dim3(128), 256, 0, stream>>>(t_img, A_cat + 384 * 512, 256 * 512 / 4);
  k_cvt_bf16<<<dim3(128), 256, 0, stream>>>(s_img, A_cat + 640 * 512, 256 * 512 / 4);

  // mega: [z | pad | t_img | s_img] @ [Wp1_top || Wp1_bot || Wi1 || Wc1_top]
  gemm_atom<1><<<dim3(32, 7, 1), 256, 0, stream>>>(A_cat, 512, Wcat, 512, 4096, 16, 16,
                                                   Facc, 4096, 0);
  k_buildH1T1<<<dim3(29696 * 128 / 256), 256, 0, stream>>>(Facc, t_attr, obj, negat,
                                                           bp1, bi1, H1, T1);

  // D2: pair_fc L2 -> X + rowsq partials  (K=1024 -> nK=32), grid 230x7
  {
    Panel s0{H1, 1024, Wp2t, 1024, bp2, 800, 832, 32, X, 832, nullptr, nullptr, 7, 0};
    gemm128<1><<<dim3(1610), 256, 0, stream>>>(s0, s0, 1 << 30, rsqP16, 29440,
                                               nullptr, nullptr, nullptr);
  }
  k_rs<<<dim3(115), 256, 0, stream>>>(rsqP16, 29440, rsP);

  // D3: compo L1 (K=832, rs+S, N=896, 230x7) + img L2 (N=1024, 2x8)
  {
    Panel s0{X, 832, Wc1bt, 832, bc1, 800, 896, 26, H2, 896, rsP,
             Facc + 640 * 4096 + 3072, 7, 0};
    Panel s1{T1, 832, Wi2t, 832, bi2, 1000, 1024, 26, T2, 1024, nullptr, nullptr, 8, 29440};
    gemm128<0><<<dim3(1626), 256, 0, stream>>>(s0, s1, 1610, nullptr, 0,
                                               nullptr, nullptr, nullptr);
  }
  // D4: compo L2 (K=896 -> nK=28, N=1024, 230x8)
  {
    Panel s0{H2, 896, Wc2t, 896, bc2, 1000, 1024, 28, H3, 1024, nullptr, nullptr, 8, 0};
    gemm128<0><<<dim3(1840), 256, 0, stream>>>(s0, s0, 1 << 30, nullptr, 0,
                                               nullptr, nullptr, nullptr);
  }
  // D5: compo L3 (theta+neg, 230x7) + img L3 (targets, 2x7), f32 out + rowsq
  {
    Panel s0{H3, 1024, Wc3t, 1024, bc3, 800, 800, 32, nullptr, 800, nullptr, nullptr, 7, 0};
    Panel s1{T2, 1024, Wi3t, 1024, bi3, 800, 800, 32, nullptr, 800, nullptr, nullptr, 7, 29440};
    gemm128<3><<<dim3(1624), 256, 0, stream>>>(s0, s1, 1610, rsqC16, 29696,
                                               cTheta, cNeg, cTgt);
  }
  k_rs<<<dim3(116), 256, 0, stream>>>(rsqC16, 29696, rsC);
  k_norm3<<<dim3(29696), 256, 0, stream>>>(cTheta, cNeg, cTgt, rsC);
}

// Round 10
// 721.808 us; speedup vs baseline: 1.2435x; 1.0034x over previous
//
#include <hip/hip_runtime.h>

// ---------------------------------------------------------------------------
// GAE_IR_79499844649397. Atomic-free pipeline.
// Big GEMMs: 128x128 tile, 4 waves, BK=32, LDS 32KB dbuf + vmcnt(4),
// slot-XOR swizzle (conflict-free), __launch_bounds__(256,4) -> 4 blocks/CU
// (56 VGPR + 64 AGPR = 120 <= 128). 1-D grid, XCD chunked swizzle, linear
// 2-panel decode. rowsq -> 14 partial slots; final rs folded into norm3.
// ---------------------------------------------------------------------------

typedef unsigned short u16;
typedef __bf16 bf16x8 __attribute__((ext_vector_type(8)));
typedef float f32x4 __attribute__((ext_vector_type(4)));

__device__ inline u16 f2bf_u(float f) {
  union { float f; unsigned u; } a; a.f = f;
  unsigned u = a.u + 0x7fffu + ((a.u >> 16) & 1u);   // RNE
  return (u16)(u >> 16);
}
__device__ inline float bf2f_u(u16 h) {
  union { unsigned u; float f; } a; a.u = ((unsigned)h) << 16; return a.f;
}

#define GLOAD16(gptr, lptr)                                                   \
  __builtin_amdgcn_global_load_lds(                                           \
      (__attribute__((address_space(1))) void*)(gptr),                        \
      (__attribute__((address_space(3))) void*)(lptr), 16, 0, 0)

#define BAR  __builtin_amdgcn_s_barrier()
#define LGKM0 asm volatile("s_waitcnt lgkmcnt(0)" ::: "memory")
#define VMC4 asm volatile("s_waitcnt vmcnt(4)" ::: "memory")
#define VMC0 asm volatile("s_waitcnt vmcnt(0)" ::: "memory")

struct Panel {
  const u16* A; int lda;
  const u16* B; int ldb;
  const float* bias; int biasN;
  int N; int nK;               // nK in units of 32
  void* out; int ldc;
  const float* rsVec;          // optional per-row scale (pre-rsqrt'd)
  const float* addS;           // optional gathered row-add (f32, ld 4096)
  int gx;                      // col-blocks (N tiles of 128)
  int rowG0;                   // global row offset of this panel
};

// MODE 0: bf16 out, v = relu(acc*rs + bias + S[b])
// MODE 1: bf16 out + bias, + rowsq partials
// MODE 3: f32 out + bias, 3-range remap + rowsq partials
template <int MODE>
__global__ __launch_bounds__(256, 4) void gemm128(
    Panel p0, Panel p1, int c0,
    float* __restrict__ rsPart, int rsLd,
    float* __restrict__ cTheta, float* __restrict__ cNeg, float* __restrict__ cTgt) {
  __shared__ u16 As[2][4096];   // [128][32] x2
  __shared__ u16 Bs[2][4096];

  // chunked-bijective XCD swizzle (1-D grid)
  const int nwg = gridDim.x;
  const int orig = blockIdx.x;
  const int q = nwg >> 3, r = nwg & 7, xcd = orig & 7;
  const int basewg = (xcd < r) ? xcd * (q + 1) : r * (q + 1) + (xcd - r) * q;
  const int wg = basewg + (orig >> 3);

  Panel P; int pby, pbx;
  if (wg < c0) { P = p0; pby = wg / p0.gx; pbx = wg - pby * p0.gx; }
  else { P = p1; const int w2 = wg - c0; pby = w2 / p1.gx; pbx = w2 - pby * p1.gx; }
  const int m0 = pby << 7, n0 = pbx << 7;

  const int tid = threadIdx.x;
  const int wave = tid >> 6, lane = tid & 63;
  const int lr = lane & 15, lg = lane >> 4;
  const int wr = wave >> 1, wc = wave & 1;

  f32x4 acc[4][4] = {};

  // staging with slot-XOR swizzle: LDS[row][sc] = G[row][sc ^ ((row>>1)&3)]
  const int r0 = tid >> 2, sc0 = tid & 3;
  const size_t aOff  = (size_t)(m0 + r0) * P.lda + ((sc0 ^ ((r0 >> 1) & 3)) << 3);
  const size_t aOff1 = (size_t)(m0 + r0 + 64) * P.lda + ((sc0 ^ (((r0 + 64) >> 1) & 3)) << 3);
  const size_t bOff  = (size_t)(n0 + r0) * P.ldb + ((sc0 ^ ((r0 >> 1) & 3)) << 3);
  const size_t bOff1 = (size_t)(n0 + r0 + 64) * P.ldb + ((sc0 ^ (((r0 + 64) >> 1) & 3)) << 3);
  const int lL = (r0 * 4 + sc0) << 4;   // byte offset within buffer (linear dest)

  auto stage = [&](int kt, int b) {
    const int k0 = kt << 5;
    GLOAD16(P.A + aOff + k0, (char*)As[b] + lL);
    GLOAD16(P.A + aOff1 + k0, (char*)As[b] + lL + 4096);
    GLOAD16(P.B + bOff + k0, (char*)Bs[b] + lL);
    GLOAD16(P.B + bOff1 + k0, (char*)Bs[b] + lL + 4096);
  };

  const int nK = P.nK;
  stage(0, 0);
  for (int kt = 0; kt < nK; ++kt) {
    const int cb = kt & 1;
    if (kt + 1 < nK) { stage(kt + 1, cb ^ 1); VMC4; }
    else { VMC0; }
    BAR;

    bf16x8 af[4], bv[4];
#pragma unroll
    for (int m = 0; m < 4; ++m) {
      const int row = (wr << 6) + (m << 4) + lr;
      af[m] = *(const bf16x8*)(&As[cb][row * 32 + ((lg ^ ((row >> 1) & 3)) << 3)]);
    }
#pragma unroll
    for (int n = 0; n < 4; ++n) {
      const int row = (wc << 6) + (n << 4) + lr;
      bv[n] = *(const bf16x8*)(&Bs[cb][row * 32 + ((lg ^ ((row >> 1) & 3)) << 3)]);
    }
#pragma unroll
    for (int m = 0; m < 4; ++m)
#pragma unroll
      for (int n = 0; n < 4; ++n)
        acc[m][n] = __builtin_amdgcn_mfma_f32_16x16x32_bf16(af[m], bv[n], acc[m][n], 0, 0, 0);

    LGKM0;
    BAR;
  }

  const int gcb = n0 + (wc << 6);
  const int grb = m0 + (wr << 6) + (lg << 2);
#pragma unroll
  for (int m = 0; m < 4; ++m) {
#pragma unroll
    for (int rr = 0; rr < 4; ++rr) {
      const int grow = grb + (m << 4) + rr;
      const int growG = P.rowG0 + grow;
      float ss = 0.f;
      float rs = 1.f;
      const float* Sp = nullptr;
      if (MODE == 0) {
        if (P.rsVec) rs = P.rsVec[growG];
        if (P.addS) {
          int bv2 = (growG < 256) ? growG : (growG - 256) / 114;
          Sp = P.addS + (size_t)bv2 * 4096;
        }
      }
#pragma unroll
      for (int n = 0; n < 4; ++n) {
        const int gc = gcb + (n << 4) + lr;
        if (gc >= P.N) continue;
        float v = acc[m][n][rr];
        if (MODE == 0) {
          v *= rs;
          if (gc < P.biasN) v += P.bias[gc];
          if (Sp) v += Sp[gc];
          v = fmaxf(v, 0.f);
          ((u16*)P.out)[(size_t)grow * P.ldc + gc] = f2bf_u(v);
        } else if (MODE == 1) {
          if (gc < P.biasN) v += P.bias[gc];
          ((u16*)P.out)[(size_t)grow * P.ldc + gc] = f2bf_u(v);
          ss += v * v;
        } else {
          if (gc < P.biasN) v += P.bias[gc];
          float* op = (growG < 256) ? cTheta + (size_t)growG * 800
                    : (growG < 29440) ? cNeg + (size_t)(growG - 256) * 800
                                      : cTgt + (size_t)(growG - 29440) * 800;
          op[gc] = v;
          ss += v * v;
        }
      }
      if (MODE == 1 || MODE == 3) {
        ss += __shfl_xor(ss, 1); ss += __shfl_xor(ss, 2);
        ss += __shfl_xor(ss, 4); ss += __shfl_xor(ss, 8);
        if (lr == 0) rsPart[(size_t)((pbx << 1) + wc) * rsLd + growG] = ss;
      }
    }
  }
}

// ---------------------------------------------------------------------------
// Small-M GEMM: 128x128, BK=32. STORE=1 plain store; else z-partial store.
// ---------------------------------------------------------------------------
template <int STORE>
__global__ __launch_bounds__(256) void gemm_atom(
    const u16* __restrict__ A, int lda, const u16* __restrict__ Bt, int ldb,
    int N, int nK, int ktChunk, float* __restrict__ Cf, int ldc, int zStride) {
  __shared__ u16 As[2][4096];
  __shared__ u16 Bs[2][4096];
  const int tid = threadIdx.x;
  const int wave = tid >> 6, lane = tid & 63;
  const int lr = lane & 15, lg = lane >> 4;
  const int wr = wave >> 1, wc = wave & 1;
  const int m0 = blockIdx.y << 7, n0 = blockIdx.x << 7;

  f32x4 acc[4][4] = {};

  const size_t aOff  = (size_t)(m0 + (tid >> 2)) * lda + ((tid & 3) << 3);
  const size_t aOff1 = aOff + (size_t)64 * lda;
  const size_t bOff  = (size_t)(n0 + (tid >> 2)) * ldb + ((tid & 3) << 3);
  const size_t bOff1 = bOff + (size_t)64 * ldb;

  const int kt0 = blockIdx.z * ktChunk;
  int ktEnd = kt0 + ktChunk; if (ktEnd > nK) ktEnd = nK;

  auto stage = [&](int kt, int b) {
    const int k0 = kt << 5;
    u16* Ad = &As[b][wave << 9];
    u16* Bd = &Bs[b][wave << 9];
    GLOAD16(A + aOff + k0, Ad);
    GLOAD16(A + aOff1 + k0, Ad + 2048);
    GLOAD16(Bt + bOff + k0, Bd);
    GLOAD16(Bt + bOff1 + k0, Bd + 2048);
  };

  if (kt0 < ktEnd) stage(kt0, 0);
  for (int kt = kt0; kt < ktEnd; ++kt) {
    const int cb = (kt - kt0) & 1;
    if (kt + 1 < ktEnd) {
      stage(kt + 1, cb ^ 1);
      VMC4;
    } else {
      VMC0;
    }
    BAR;
    asm volatile("" ::: "memory");

    bf16x8 af[4], bvv[4];
#pragma unroll
    for (int m = 0; m < 4; ++m)
      af[m] = *(const bf16x8*)(&As[cb][(((wr << 6) + (m << 4) + lr) << 5) + (lg << 3)]);
#pragma unroll
    for (int n = 0; n < 4; ++n)
      bvv[n] = *(const bf16x8*)(&Bs[cb][(((wc << 6) + (n << 4) + lr) << 5) + (lg << 3)]);
#pragma unroll
    for (int m = 0; m < 4; ++m)
#pragma unroll
      for (int n = 0; n < 4; ++n)
        acc[m][n] = __builtin_amdgcn_mfma_f32_16x16x32_bf16(af[m], bvv[n], acc[m][n], 0, 0, 0);

    asm volatile("s_waitcnt lgkmcnt(0)" ::: "memory");
    BAR;
    asm volatile("" ::: "memory");
  }

  float* out = STORE ? Cf : (Cf + (size_t)blockIdx.z * zStride);
  const int gcb = n0 + (wc << 6);
  const int grb = m0 + (wr << 6) + (lg << 2);
#pragma unroll
  for (int m = 0; m < 4; ++m)
#pragma unroll
    for (int rr = 0; rr < 4; ++rr) {
      const int grow = grb + (m << 4) + rr;
#pragma unroll
      for (int n = 0; n < 4; ++n) {
        const int gc = gcb + (n << 4) + lr;
        if (gc < N) out[(size_t)grow * ldc + gc] = acc[m][n][rr];
      }
    }
}

// --------------------------- weight packing --------------------------------
struct PJob { const float* src; u16* dst; int Ksrc, Nsrc, Kpad, Npad, ld; };
struct PJobs { PJob j[10]; };

__global__ void k_pack10(PJobs J) {
  PJob job = J.j[blockIdx.z];
  const int k0 = blockIdx.x * 16, n0 = blockIdx.y * 16;
  if (k0 >= job.Kpad || n0 >= job.Npad) return;
  __shared__ float t[16][17];
  const int tx = threadIdx.x, ty = threadIdx.y;
  const int km = k0 + ty, n = n0 + tx;
  float v = (km < job.Ksrc && n < job.Nsrc) ? job.src[(size_t)km * job.Nsrc + n] : 0.f;
  t[ty][tx] = v;
  __syncthreads();
  if (k0 + tx < job.Kpad && n0 + ty < job.Npad)
    job.dst[(size_t)(n0 + ty) * job.ld + k0 + tx] = f2bf_u(t[tx][ty]);
}

// Split-bf16 stacked pack: W[Ktot][Nsrc] = [srcA(splitK); srcB]; k blocks [hi,hi,lo].
__global__ void k_pack_split(const float* __restrict__ srcA, const float* __restrict__ srcB,
                             int splitK, int Ktot, int Nsrc,
                             u16* __restrict__ dst, int dstLd) {
  __shared__ float t[16][17];
  const int k0 = blockIdx.x * 16, n0 = blockIdx.y * 16;
  const int tx = threadIdx.x, ty = threadIdx.y;
  int kOut = k0 + ty;
  int blk = kOut / Ktot; int km = kOut - blk * Ktot;
  const int n = n0 + tx;
  float v = 0.f;
  if (n < Nsrc)
    v = (km < splitK) ? srcA[(size_t)km * Nsrc + n]
                      : srcB[(size_t)(km - splitK) * Nsrc + n];
  t[ty][tx] = v;
  __syncthreads();
  const int kw = k0 + tx;
  const int blkw = kw / Ktot;
  float x = t[tx][ty];
  u16 hb = f2bf_u(x);
  u16 o = (blkw == 2) ? f2bf_u(x - bf2f_u(hb)) : hb;
  dst[(size_t)(n0 + ty) * dstLd + kw] = o;
}

// ---------------- SAGE aggregation (atomic-free per-node scan) -------------
__global__ void k_aggpack1(const int* __restrict__ es, const int* __restrict__ ed,
                           const float* __restrict__ nodes, u16* __restrict__ Agp) {
  const int node = blockIdx.x;              // 0..383
  const int c = threadIdx.x * 2;
  u16* row = Agp + (size_t)node * 3072;
  if (node >= 360) {
#pragma unroll
    for (int b = 0; b < 3; ++b) { row[b * 1024 + c] = 0; row[b * 1024 + c + 1] = 0;
                                  row[b * 1024 + 512 + c] = 0; row[b * 1024 + 512 + c + 1] = 0; }
    return;
  }
  float a0 = 0.f, a1 = 0.f, cnt = 0.f;
  for (int e = 0; e < 1262; ++e) {
    if (ed[e] == node) {
      const float* xr = nodes + (size_t)es[e] * 512;
      a0 += xr[c]; a1 += xr[c + 1]; cnt += 1.f;
    }
  }
  float inv = 1.f / fmaxf(cnt, 1.f);
  a0 *= inv; a1 *= inv;
  float x0 = nodes[(size_t)node * 512 + c], x1 = nodes[(size_t)node * 512 + c + 1];
  u16 ah0 = f2bf_u(a0), ah1 = f2bf_u(a1);
  u16 al0 = f2bf_u(a0 - bf2f_u(ah0)), al1 = f2bf_u(a1 - bf2f_u(ah1));
  u16 xh0 = f2bf_u(x0), xh1 = f2bf_u(x1);
  u16 xl0 = f2bf_u(x0 - bf2f_u(xh0)), xl1 = f2bf_u(x1 - bf2f_u(xh1));
  row[c] = ah0; row[c + 1] = ah1; row[512 + c] = xh0; row[512 + c + 1] = xh1;
  row[1024 + c] = al0; row[1024 + c + 1] = al1; row[1536 + c] = xl0; row[1536 + c + 1] = xl1;
  row[2048 + c] = ah0; row[2048 + c + 1] = ah1; row[2560 + c] = xh0; row[2560 + c + 1] = xh1;
}

__global__ void k_aggpack2(const int* __restrict__ es, const int* __restrict__ ed,
                           const float* __restrict__ Hf, u16* __restrict__ A2p) {
  const int node = blockIdx.x;              // 0..383
  const int c = threadIdx.x * 8;
  u16* row = A2p + (size_t)node * 12288;
  if (node >= 360) {
#pragma unroll
    for (int b = 0; b < 3; ++b)
      for (int j = 0; j < 8; ++j) { row[b * 4096 + c + j] = 0; row[b * 4096 + 2048 + c + j] = 0; }
    return;
  }
  float a[8] = {}; float cnt = 0.f;
  for (int e = 0; e < 1262; ++e) {
    if (ed[e] == node) {
      const float* hr = Hf + (size_t)es[e] * 2048 + c;
      float4 v0 = *(const float4*)hr, v1 = *(const float4*)(hr + 4);
      a[0] += v0.x; a[1] += v0.y; a[2] += v0.z; a[3] += v0.w;
      a[4] += v1.x; a[5] += v1.y; a[6] += v1.z; a[7] += v1.w;
      cnt += 1.f;
    }
  }
  float inv = 1.f / fmaxf(cnt, 1.f);
  const float* hx = Hf + (size_t)node * 2048 + c;
#pragma unroll
  for (int j = 0; j < 8; ++j) {
    float av = a[j] * inv, xv = hx[j];
    u16 ah = f2bf_u(av), xh = f2bf_u(xv);
    u16 al = f2bf_u(av - bf2f_u(ah)), xl = f2bf_u(xv - bf2f_u(xh));
    row[c + j] = ah; row[2048 + c + j] = xh;
    row[4096 + c + j] = al; row[6144 + c + j] = xl;
    row[8192 + c + j] = ah; row[10240 + c + j] = xh;
  }
}

// partial-sum + bias kernels
__global__ void k_relu_bias_f32(const float* __restrict__ acc, const float* __restrict__ bias,
                                float* __restrict__ out, int N, int total, int nz, int zs) {
  int idx = blockIdx.x * 256 + threadIdx.x;
  if (idx >= total) return;
  float s = 0.f;
  for (int z = 0; z < nz; ++z) s += acc[(size_t)z * zs + idx];
  out[idx] = fmaxf(s + bias[idx % N], 0.f);
}
__global__ void k_bias_bf16(const float* __restrict__ acc, const float* __restrict__ bias,
                            u16* __restrict__ out, int N, int total, int nz, int zs) {
  int idx = blockIdx.x * 256 + threadIdx.x;
  if (idx >= total) return;
  float s = 0.f;
  for (int z = 0; z < nz; ++z) s += acc[(size_t)z * zs + idx];
  out[idx] = f2bf_u(s + bias[idx % N]);
}

__global__ void k_cvt_bf16(const float* __restrict__ src, u16* __restrict__ dst, int n4) {
  int idx = blockIdx.x * 256 + threadIdx.x;
  if (idx >= n4) return;
  float4 v = *(const float4*)(src + ((size_t)idx << 2));
  ushort4 o;
  o.x = f2bf_u(v.x); o.y = f2bf_u(v.y); o.z = f2bf_u(v.z); o.w = f2bf_u(v.w);
  *(ushort4*)(dst + ((size_t)idx << 2)) = o;
}

// H1[r][c<1000] = relu(F[a(r)][c] + G[115+o(r)][c] + bp1[c]); pad 0 to 1024.
// T1[rt][c<800] = relu(I1[rt][c] + bi1[c]); pad 0 to 832.
__global__ void k_buildH1T1(const float* __restrict__ Facc,
                            const int* __restrict__ t_attr, const int* __restrict__ obj,
                            const int* __restrict__ negat, const float* __restrict__ bp1,
                            const float* __restrict__ bi1,
                            u16* __restrict__ H1, u16* __restrict__ T1) {
  int idx = blockIdx.x * 256 + threadIdx.x;
  if (idx >= 29696 * 128) return;
  int r = idx >> 7, ch = idx & 127, c = ch << 3;
  if (r < 29440) {
    u16* dst = H1 + ((size_t)r << 10) + c;
    if (c >= 1000) { ushort4 z = {0,0,0,0}; *(ushort4*)dst = z; *(ushort4*)(dst + 4) = z; return; }
    int a, o;
    if (r < 256) { a = t_attr[r]; o = obj[r]; }
    else { int rr = r - 256; a = negat[rr]; o = obj[rr / 114]; }
    const float* Fa = Facc + (size_t)a * 4096 + c;
    const float* Go = Facc + (size_t)(115 + o) * 4096 + 1024 + c;
    const float* Bp = bp1 + c;
    ushort4 o0, o1;
    float4 f0 = *(const float4*)Fa, f1 = *(const float4*)(Fa + 4);
    float4 g0 = *(const float4*)Go, g1 = *(const float4*)(Go + 4);
    float4 b0 = *(const float4*)Bp, b1 = *(const float4*)(Bp + 4);
    o0.x = f2bf_u(fmaxf(f0.x + g0.x + b0.x, 0.f));
    o0.y = f2bf_u(fmaxf(f0.y + g0.y + b0.y, 0.f));
    o0.z = f2bf_u(fmaxf(f0.z + g0.z + b0.z, 0.f));
    o0.w = f2bf_u(fmaxf(f0.w + g0.w + b0.w, 0.f));
    o1.x = f2bf_u(fmaxf(f1.x + g1.x + b1.x, 0.f));
    o1.y = f2bf_u(fmaxf(f1.y + g1.y + b1.y, 0.f));
    o1.z = f2bf_u(fmaxf(f1.z + g1.z + b1.z, 0.f));
    o1.w = f2bf_u(fmaxf(f1.w + g1.w + b1.w, 0.f));
    *(ushort4*)dst = o0; *(ushort4*)(dst + 4) = o1;
  } else {
    int rt = r - 29440;
    if (ch >= 104) return;
    u16* dst = T1 + (size_t)rt * 832 + c;
    if (c >= 800) { ushort4 z = {0,0,0,0}; *(ushort4*)dst = z; *(ushort4*)(dst + 4) = z; return; }
    const float* I1 = Facc + (size_t)(384 + rt) * 4096 + 2048 + c;
    const float* Bi = bi1 + c;
    float4 f0 = *(const float4*)I1, f1 = *(const float4*)(I1 + 4);
    float4 b0 = *(const float4*)Bi, b1 = *(const float4*)(Bi + 4);
    ushort4 o0, o1;
    o0.x = f2bf_u(fmaxf(f0.x + b0.x, 0.f)); o0.y = f2bf_u(fmaxf(f0.y + b0.y, 0.f));
    o0.z = f2bf_u(fmaxf(f0.z + b0.z, 0.f)); o0.w = f2bf_u(fmaxf(f0.w + b0.w, 0.f));
    o1.x = f2bf_u(fmaxf(f1.x + b1.x, 0.f)); o1.y = f2bf_u(fmaxf(f1.y + b1.y, 0.f));
    o1.z = f2bf_u(fmaxf(f1.z + b1.z, 0.f)); o1.w = f2bf_u(fmaxf(f1.w + b1.w, 0.f));
    *(ushort4*)dst = o0; *(ushort4*)(dst + 4) = o1;
  }
}

// reduce 14 partials -> rs = rsqrt(sum)
__global__ void k_rs(const float* __restrict__ part, int nrows, float* __restrict__ rs) {
  int idx = blockIdx.x * 256 + threadIdx.x;
  if (idx >= nrows) return;
  float s = 0.f;
#pragma unroll
  for (int i = 0; i < 14; ++i) s += part[(size_t)i * nrows + idx];
  rs[idx] = rsqrtf(fmaxf(s, 1e-24f));
}

// scale the three f32 output regions; rs computed inline from 14 partials
__global__ void k_norm3(float* __restrict__ cTheta, float* __restrict__ cNeg,
                        float* __restrict__ cTgt, const float* __restrict__ part,
                        int nrows) {
  int r = blockIdx.x;
  float ssum = 0.f;
#pragma unroll
  for (int i = 0; i < 14; ++i) ssum += part[(size_t)i * nrows + r];
  float s = rsqrtf(fmaxf(ssum, 1e-24f));
  float* row = (r < 256) ? cTheta + (size_t)r * 800
             : (r < 29440) ? cNeg + (size_t)(r - 256) * 800
                           : cTgt + (size_t)(r - 29440) * 800;
  int c = threadIdx.x;
  if (c < 200) {
    float4 v = *(float4*)(row + (c << 2));
    v.x *= s; v.y *= s; v.z *= s; v.w *= s;
    *(float4*)(row + (c << 2)) = v;
  }
}

// ---------------------------------------------------------------------------
extern "C" void kernel_launch(void* const* d_in, const int* in_sizes, int n_in,
                              void* d_out, int out_size, void* d_ws, size_t ws_size,
                              hipStream_t stream) {
  const float* nodes = (const float*)d_in[0];
  const float* s_img = (const float*)d_in[1];
  const float* t_img = (const float*)d_in[2];
  const float* Wl1 = (const float*)d_in[3];
  const float* Wr1 = (const float*)d_in[4];
  const float* b1  = (const float*)d_in[5];
  const float* Wl2 = (const float*)d_in[6];
  const float* Wr2 = (const float*)d_in[7];
  const float* b2  = (const float*)d_in[8];
  const float* Wp1 = (const float*)d_in[9];
  const float* bp1 = (const float*)d_in[10];
  const float* Wp2 = (const float*)d_in[11];
  const float* bp2 = (const float*)d_in[12];
  const float* Wi1 = (const float*)d_in[13];
  const float* bi1 = (const float*)d_in[14];
  const float* Wi2 = (const float*)d_in[15];
  const float* bi2 = (const float*)d_in[16];
  const float* Wi3 = (const float*)d_in[17];
  const float* bi3 = (const float*)d_in[18];
  const float* Wc1 = (const float*)d_in[19];
  const float* bc1 = (const float*)d_in[20];
  const float* Wc2 = (const float*)d_in[21];
  const float* bc2 = (const float*)d_in[22];
  const float* Wc3 = (const float*)d_in[23];
  const float* bc3 = (const float*)d_in[24];
  const int* e_src = (const int*)d_in[25];
  const int* e_dst = (const int*)d_in[26];
  const int* t_attr = (const int*)d_in[27];
  const int* obj    = (const int*)d_in[28];
  const int* negat  = (const int*)d_in[29];
  (void)in_sizes; (void)n_in; (void)out_size; (void)ws_size;

  float* out = (float*)d_out;
  float* cTheta = out;
  float* cTgt = out + 204800;
  float* cNeg = out + 409600;

  char* p = (char*)d_ws;
  auto alloc = [&](size_t bytes) -> void* {
    char* r = p; p += (bytes + 255) & ~(size_t)255; return (void*)r;
  };
  u16* W1t   = (u16*)alloc(2048ull * 3072 * 2);
  u16* W2t   = (u16*)alloc(512ull * 12288 * 2);
  u16* Wp2t  = (u16*)alloc(1024ull * 1024 * 2);
  u16* Wc1bt = (u16*)alloc(1024ull * 832 * 2);
  u16* Wc2t  = (u16*)alloc(1024ull * 896 * 2);
  u16* Wc3t  = (u16*)alloc(1024ull * 1024 * 2);
  u16* Wi2t  = (u16*)alloc(1024ull * 832 * 2);
  u16* Wi3t  = (u16*)alloc(1024ull * 1024 * 2);
  u16* Wcat  = (u16*)alloc(4096ull * 512 * 2);
  u16* Agp   = (u16*)alloc(384ull * 3072 * 2);
  float* Hacc = (float*)alloc(4ull * 384 * 2048 * 4);
  float* Hf   = (float*)alloc(384ull * 2048 * 4);
  u16* A2p   = (u16*)alloc(384ull * 12288 * 2);
  float* Zacc = (float*)alloc(8ull * 384 * 512 * 4);
  u16* A_cat = (u16*)alloc(896ull * 512 * 2);
  float* Facc = (float*)alloc(896ull * 4096 * 4);
  u16* T1    = (u16*)alloc(256ull * 832 * 2);
  u16* T2    = (u16*)alloc(256ull * 1024 * 2);
  float* rsqP16 = (float*)alloc(16ull * 29440 * 4);
  float* rsqC16 = (float*)alloc(16ull * 29696 * 4);
  float* rsP = (float*)alloc(29440ull * 4);
  u16* H1 = (u16*)alloc(29440ull * 1024 * 2);
  u16* X  = (u16*)alloc(29440ull * 832 * 2);
  u16* H3 = (u16*)alloc(29440ull * 1024 * 2);
  u16* H2 = H1;   // [29440][896] aliases H1 (dead after D2)

  dim3 tb(16, 16);
  k_pack_split<<<dim3(192, 128), tb, 0, stream>>>(Wl1, Wr1, 512, 1024, 2048, W1t, 3072);
  k_pack_split<<<dim3(768, 32), tb, 0, stream>>>(Wl2, Wr2, 2048, 4096, 512, W2t, 12288);
  {
    PJobs J;
    J.j[0] = {Wp2, Wp2t, 1000, 800, 1024, 1024, 1024};
    J.j[1] = {Wc1 + 512 * 800, Wc1bt, 800, 800, 832, 1024, 832};
    J.j[2] = {Wc2, Wc2t, 800, 1000, 896, 1024, 896};
    J.j[3] = {Wc3, Wc3t, 1000, 800, 1024, 1024, 1024};
    J.j[4] = {Wi2, Wi2t, 800, 1000, 832, 1024, 832};
    J.j[5] = {Wi3, Wi3t, 1000, 800, 1024, 1024, 1024};
    J.j[6] = {Wp1, Wcat, 512, 1000, 512, 1024, 512};
    J.j[7] = {Wp1 + 512 * 1000, Wcat + 1024 * 512, 512, 1000, 512, 1024, 512};
    J.j[8] = {Wi1, Wcat + 2048 * 512, 512, 800, 512, 1024, 512};
    J.j[9] = {Wc1, Wcat + 3072 * 512, 512, 800, 512, 1024, 512};
    k_pack10<<<dim3(64, 64, 10), tb, 0, stream>>>(J);
  }

  // SAGE
  k_aggpack1<<<dim3(384), 256, 0, stream>>>(e_src, e_dst, nodes, Agp);
  gemm_atom<0><<<dim3(16, 3, 4), 256, 0, stream>>>(Agp, 3072, W1t, 3072, 2048, 96, 24,
                                                   Hacc, 2048, 384 * 2048);
  k_relu_bias_f32<<<dim3(384 * 2048 / 256), 256, 0, stream>>>(Hacc, b1, Hf, 2048,
                                                              384 * 2048, 4, 384 * 2048);
  k_aggpack2<<<dim3(384), 256, 0, stream>>>(e_src, e_dst, Hf, A2p);
  gemm_atom<0><<<dim3(4, 3, 8), 256, 0, stream>>>(A2p, 12288, W2t, 12288, 512, 384, 48,
                                                  Zacc, 512, 384 * 512);
  k_bias_bf16<<<dim3(384 * 512 / 256), 256, 0, stream>>>(Zacc, b2, A_cat, 512,
                                                         384 * 512, 8, 384 * 512);
  k_cvt_bf16<<<dim3(128), 256, 0, stream>>>(t_img, A_cat + 384 * 512, 256 * 512 / 4);
  k_cvt_bf16<<<dim3(128), 256, 0, stream>>>(s_img, A_cat + 640 * 512, 256 * 512 / 4);

  // mega: [z | pad | t_img | s_img] @ [Wp1_top || Wp1_bot || Wi1 || Wc1_top]
  gemm_atom<1><<<dim3(32, 7, 1), 256, 0, stream>>>(A_cat, 512, Wcat, 512, 4096, 16, 16,
                                                   Facc, 4096, 0);
  k_buildH1T1<<<dim3(29696 * 128 / 256), 256, 0, stream>>>(Facc, t_attr, obj, negat,
                                                           bp1, bi1, H1, T1);

  // D2: pair_fc L2 -> X + rowsq partials  (K=1024 -> nK=32), grid 230x7
  {
    Panel s0{H1, 1024, Wp2t, 1024, bp2, 800, 832, 32, X, 832, nullptr, nullptr, 7, 0};
    gemm128<1><<<dim3(1610), 256, 0, stream>>>(s0, s0, 1 << 30, rsqP16, 29440,
                                               nullptr, nullptr, nullptr);
  }
  k_rs<<<dim3(115), 256, 0, stream>>>(rsqP16, 29440, rsP);

  // D3: compo L1 (K=832, rs+S, N=896, 230x7) + img L2 (N=1024, 2x8)
  {
    Panel s0{X, 832, Wc1bt, 832, bc1, 800, 896, 26, H2, 896, rsP,
             Facc + 640 * 4096 + 3072, 7, 0};
    Panel s1{T1, 832, Wi2t, 832, bi2, 1000, 1024, 26, T2, 1024, nullptr, nullptr, 8, 29440};
    gemm128<0><<<dim3(1626), 256, 0, stream>>>(s0, s1, 1610, nullptr, 0,
                                               nullptr, nullptr, nullptr);
  }
  // D4: compo L2 (K=896 -> nK=28, N=1024, 230x8)
  {
    Panel s0{H2, 896, Wc2t, 896, bc2, 1000, 1024, 28, H3, 1024, nullptr, nullptr, 8, 0};
    gemm128<0><<<dim3(1840), 256, 0, stream>>>(s0, s0, 1 << 30, nullptr, 0,
                                               nullptr, nullptr, nullptr);
  }
  // D5: compo L3 (theta+neg, 230x7) + img L3 (targets, 2x7), f32 out + rowsq
  {
    Panel s0{H3, 1024, Wc3t, 1024, bc3, 800, 800, 32, nullptr, 800, nullptr, nullptr, 7, 0};
    Panel s1{T2, 1024, Wi3t, 1024, bi3, 800, 800, 32, nullptr, 800, nullptr, nullptr, 7, 29440};
    gemm128<3><<<dim3(1624), 256, 0, stream>>>(s0, s1, 1610, rsqC16, 29696,
                                               cTheta, cNeg, cTgt);
  }
  k_norm3<<<dim3(29696), 256, 0, stream>>>(cTheta, cNeg, cTgt, rsqC16, 29696);
}